// Round 4
// baseline (231.058 us; speedup 1.0000x reference)
//
#include <hip/hip_runtime.h>

#define SS 1024
#define DD 512
#define BATCH 8
#define MIN_T 0.1f
#define MAX_T 0.9f

using half8  = __attribute__((ext_vector_type(8))) _Float16;
using floatx4 = __attribute__((ext_vector_type(4))) float;

typedef const __attribute__((address_space(1))) void gvoid;
typedef __attribute__((address_space(3))) void lvoid;

// ---------------- row-sum of pruned fp16 matrix -> rden = 1/(sum+1) ----------------
__global__ void rsum_k(const _Float16* __restrict__ A, float* __restrict__ rden, int rows) {
    int row = blockIdx.x * 4 + (threadIdx.x >> 6);
    if (row >= rows) return;
    int lane = threadIdx.x & 63;
    const _Float16* a = A + (size_t)row * SS;
    float s = 0.f;
#pragma unroll
    for (int r = 0; r < 2; ++r) {
        half8 v = *(const half8*)&a[(lane + 64 * r) * 8];
#pragma unroll
        for (int j = 0; j < 8; ++j) s += (float)v[j];
    }
#pragma unroll
    for (int m = 32; m > 0; m >>= 1) s += __shfl_xor(s, m, 64);
    if (lane == 0) rden[row] = 1.0f / (s + 1.0f);
}

// ---------------- generic cast / prune / transpose prep ----------------
template <typename ST, bool PRUNE, bool DON, bool DOT>
__global__ void prep_k(const ST* __restrict__ src, int sld, long bS,
                       _Float16* __restrict__ dN, int ldN, long bN,
                       _Float16* __restrict__ dT, int ldT, long bT,
                       int srcR, int srcC, int dTR, int dTC) {
    __shared__ float lt[64][65];
    src += (size_t)blockIdx.z * bS;
    int c0 = blockIdx.x * 64, r0 = blockIdx.y * 64;
    int tx = threadIdx.x, ty = threadIdx.y;  // 64 x 4
#pragma unroll
    for (int it = 0; it < 16; ++it) {
        int r = r0 + ty + it * 4, c = c0 + tx;
        float v = 0.f;
        if (r < srcR && c < srcC) v = (float)src[(size_t)r * sld + c];
        if (PRUNE) v = (v >= MIN_T && v <= MAX_T) ? v : 0.f;
        if (DON) {
            if (r < srcR && c < srcC)
                dN[(size_t)blockIdx.z * bN + (size_t)r * ldN + c] = (_Float16)v;
        }
        if (DOT) lt[tx][ty + it * 4] = v;
    }
    if (DOT) {
        __syncthreads();
#pragma unroll
        for (int it = 0; it < 16; ++it) {
            int tr = c0 + ty + it * 4, tc = r0 + tx;
            if (tr < dTR && tc < dTC)
                dT[(size_t)blockIdx.z * bT + (size_t)tr * ldT + tc] =
                    (_Float16)lt[ty + it * 4][tx];
        }
    }
}

__global__ void ubias_k(const float* __restrict__ U, float* __restrict__ ub) {
    int n = blockIdx.x * 64 + threadIdx.x;
    if (n < 576) ub[n] = (n < 513) ? U[512 * 513 + n] : 0.f;
}

// ---------------- MFMA GEMM: C = A[M][K] * B[N][K]^T, fp16 in / fp32 acc ----------------
// 128x128 tile, 512 threads = 8 waves (2 row-groups x 4 col-groups), 64x32 per wave.
// EPI: 1 = agg + fp16X add (C fp16), 2 = wmm relu((acc+bias)*rden) (C fp16),
//      3 = t1 acc+Ubias[n], store guard n<N (C fp16), 4 = score acc+(float)tb[m*e0ld] (C fp32)
constexpr int GBM = 128, GBN = 128, GBK = 64;

template <int EPI>
__global__ __launch_bounds__(512, 4) void gemm_k(
    const _Float16* __restrict__ A, const _Float16* __restrict__ B, void* __restrict__ Cv,
    int M, int N, int K, int lda, int ldb, int ldc,
    long bA, long bB, long bC,
    const void* __restrict__ e0, int e0ld, long bE0, const float* __restrict__ e1) {
    __shared__ _Float16 lA[2][GBM * GBK];  // [128][64], 8x16B chunks/row, source-swizzled
    __shared__ _Float16 lB[2][GBN * GBK];  // [128][64]

    const int z = blockIdx.z;
    A += (size_t)z * bA;
    B += (size_t)z * bB;
    const int m0 = blockIdx.x * GBM, n0 = blockIdx.y * GBN;
    const int tid = threadIdx.x;
    const int lane = tid & 63, wv = tid >> 6;
    const int wr = wv >> 2, wc = wv & 3;  // 2x4 waves, 64x32 per wave

    auto stage = [&](int buf, int kt) {
#pragma unroll
        for (int it = 0; it < 2; ++it) {  // A: 1024 chunks
            int q = it * 512 + tid;
            int r = q >> 3, cp = q & 7, cl = cp ^ (r & 7);
            const _Float16* g = A + (size_t)(m0 + r) * lda + kt + cl * 8;
            __builtin_amdgcn_global_load_lds((gvoid*)g,
                (lvoid*)(&lA[buf][(it * 512 + wv * 64) * 8]), 16, 0, 0);
        }
#pragma unroll
        for (int it = 0; it < 2; ++it) {  // B: 1024 chunks
            int q = it * 512 + tid;
            int r = q >> 3, cp = q & 7, cl = cp ^ (r & 7);
            const _Float16* g = B + (size_t)(n0 + r) * ldb + kt + cl * 8;
            __builtin_amdgcn_global_load_lds((gvoid*)g,
                (lvoid*)(&lB[buf][(it * 512 + wv * 64) * 8]), 16, 0, 0);
        }
    };

    floatx4 acc[4][2] = {};

    stage(0, 0);
    asm volatile("s_waitcnt vmcnt(0)");
    __syncthreads();
    int cur = 0;
    for (int kt = 0; kt < K; kt += GBK) {
        int nxt = kt + GBK;
        if (nxt < K) stage(cur ^ 1, nxt);
#pragma unroll
        for (int kk = 0; kk < 2; ++kk) {
            half8 af[4], bf[2];
#pragma unroll
            for (int i = 0; i < 4; ++i) {
                int row = wr * 64 + i * 16 + (lane & 15);
                int cl = kk * 4 + (lane >> 4);
                int cp = cl ^ (row & 7);
                af[i] = *(const half8*)&lA[cur][row * 64 + cp * 8];
            }
#pragma unroll
            for (int j = 0; j < 2; ++j) {
                int row = wc * 32 + j * 16 + (lane & 15);
                int cl = kk * 4 + (lane >> 4);
                int cp = cl ^ (row & 7);
                bf[j] = *(const half8*)&lB[cur][row * 64 + cp * 8];
            }
#pragma unroll
            for (int i = 0; i < 4; ++i)
#pragma unroll
                for (int j = 0; j < 2; ++j)
                    acc[i][j] = __builtin_amdgcn_mfma_f32_16x16x32_f16(af[i], bf[j], acc[i][j], 0, 0, 0);
        }
        if (nxt < K) {
            asm volatile("s_waitcnt vmcnt(0)");
            __syncthreads();
        }
        cur ^= 1;
    }

    // epilogue: C map col=lane&15, row=(lane>>4)*4+r
    const int cm = (lane >> 4) * 4;
    const int cn = lane & 15;
#pragma unroll
    for (int i = 0; i < 4; ++i) {
#pragma unroll
        for (int j = 0; j < 2; ++j) {
#pragma unroll
            for (int r = 0; r < 4; ++r) {
                int m = m0 + wr * 64 + i * 16 + cm + r;
                int n = n0 + wc * 32 + j * 16 + cn;
                float v = acc[i][j][r];
                if constexpr (EPI == 1) {
                    const _Float16* X = (const _Float16*)e0 + (size_t)z * bE0;
                    v += (float)X[(size_t)m * e0ld + n];
                    ((_Float16*)Cv)[(size_t)z * bC + (size_t)m * ldc + n] = (_Float16)v;
                } else if constexpr (EPI == 2) {
                    v = (v + ((const float*)e0)[n]) * e1[m];
                    v = v > 0.f ? v : 0.f;
                    ((_Float16*)Cv)[(size_t)z * bC + (size_t)m * ldc + n] = (_Float16)v;
                } else if constexpr (EPI == 3) {
                    if (n < N) {
                        v += ((const float*)e0)[n];
                        ((_Float16*)Cv)[(size_t)z * bC + (size_t)m * ldc + n] = (_Float16)v;
                    }
                } else {
                    const _Float16* tb = (const _Float16*)e0 + (size_t)z * bE0;
                    v += (float)tb[(size_t)m * e0ld];
                    ((float*)Cv)[(size_t)z * bC + (size_t)m * ldc + n] = v;
                }
            }
        }
    }
}

extern "C" void kernel_launch(void* const* d_in, const int* in_sizes, int n_in,
                              void* d_out, int out_size, void* d_ws, size_t ws_size,
                              hipStream_t stream) {
    const float* x0  = (const float*)d_in[0];  // [B,S,D]
    const float* adj = (const float*)d_in[1];  // [B,S,S]
    const float* W1  = (const float*)d_in[2];  // [L,D,D]
    const float* b1  = (const float*)d_in[3];  // [L,D]
    const float* W2  = (const float*)d_in[4];
    const float* b2  = (const float*)d_in[5];
    const float* U   = (const float*)d_in[6];  // [1,513,513]
    float* out = (float*)d_out;

    char* ws = (char*)d_ws;
    const size_t MB = 1u << 20;
    _Float16* adjH  = (_Float16*)(ws);             // 16 MB pruned fp16 adj
    _Float16* adjHT = (_Float16*)(ws + 16 * MB);   // 16 MB pruned fp16 adj^T
    _Float16* u0  = (_Float16*)(ws + 32 * MB);     // x0^T fp16
    _Float16* u1  = (_Float16*)(ws + 40 * MB);     // Yh
    _Float16* u2  = (_Float16*)(ws + 48 * MB);     // Xh / h2
    _Float16* u3  = (_Float16*)(ws + 56 * MB);     // Xh^T
    _Float16* u4  = (_Float16*)(ws + 64 * MB);     // h1
    _Float16* x0h = (_Float16*)(ws + 72 * MB);     // x0 fp16 natural
    _Float16* t1h = (_Float16*)(ws + 80 * MB);     // [8192][576] 9.44 MB
    _Float16* W1T = (_Float16*)(ws + 90 * MB);     // 1 MB
    _Float16* W2T = (_Float16*)(ws + 91 * MB);     // 1 MB
    _Float16* UT  = (_Float16*)(ws + 92 * MB);     // [640][512] zero-padded, 0.64 MB
    float* Ubias  = (float*)(ws + 93 * MB);
    float* rden1  = (float*)(ws + 93 * MB + 16384);
    float* rden2  = rden1 + BATCH * SS;

    dim3 tb(64, 4);
    // weight / U / x0 preps
    prep_k<float, false, false, true><<<dim3(8, 8, 2), tb, 0, stream>>>(
        W1, DD, (long)DD * DD, nullptr, 0, 0, W1T, DD, (long)DD * DD, DD, DD, DD, DD);
    prep_k<float, false, false, true><<<dim3(8, 8, 2), tb, 0, stream>>>(
        W2, DD, (long)DD * DD, nullptr, 0, 0, W2T, DD, (long)DD * DD, DD, DD, DD, DD);
    prep_k<float, false, false, true><<<dim3(10, 8, 1), tb, 0, stream>>>(
        U, 513, 0, nullptr, 0, 0, UT, DD, 0, 512, 513, 640, 512);
    ubias_k<<<9, 64, 0, stream>>>(U, Ubias);
    prep_k<float, false, true, true><<<dim3(8, 16, BATCH), tb, 0, stream>>>(
        x0, DD, (long)SS * DD, x0h, DD, (long)SS * DD, u0, SS, (long)SS * DD, SS, DD, DD, SS);
    // pruned adjacency: natural + transposed in ONE fp32 pass
    const long bAdj = (long)SS * SS, bAct = (long)SS * DD;
    prep_k<float, true, true, true><<<dim3(16, 16, BATCH), tb, 0, stream>>>(
        adj, SS, bAdj, adjH, SS, bAdj, adjHT, SS, bAdj, SS, SS, SS, SS);
    rsum_k<<<BATCH * SS / 4, 256, 0, stream>>>(adjH, rden1, BATCH * SS);
    rsum_k<<<BATCH * SS / 4, 256, 0, stream>>>(adjHT, rden2, BATCH * SS);

    dim3 gAgg(SS / GBM, DD / GBN, BATCH);        // (8,4,8)
    dim3 gWmm(BATCH * SS / GBM, DD / GBN, 1);    // (64,4)
    dim3 gT1(BATCH * SS / GBM, 5, 1);            // (64,5)  N padded to 640
    dim3 gSc(SS / GBM, SS / GBN, BATCH);         // (8,8,8)

    for (int st = 0; st < 2; ++st) {
        const _Float16* adjS = st == 0 ? adjH : adjHT;
        const _Float16* WT = st == 0 ? W1T : W2T;
        const float* bias = st == 0 ? b1 : b2;
        const float* rden = st == 0 ? rden1 : rden2;
        _Float16* hout = st == 0 ? u4 : u2;
        // layer 0: Y = A*x0 + x0
        gemm_k<1><<<gAgg, 512, 0, stream>>>(adjS, u0, u1, SS, DD, SS, SS, SS, DD,
                                            bAdj, bAct, bAct, x0h, DD, bAct, nullptr);
        gemm_k<2><<<gWmm, 512, 0, stream>>>(u1, WT, u2, BATCH * SS, DD, DD, DD, DD, DD,
                                            0, 0, 0, bias, 0, 0, rden);
        // transpose activations for next aggregation
        prep_k<_Float16, false, false, true><<<dim3(8, 16, BATCH), tb, 0, stream>>>(
            u2, DD, bAct, nullptr, 0, 0, u3, SS, bAct, SS, DD, DD, SS);
        // layer 1
        gemm_k<1><<<gAgg, 512, 0, stream>>>(adjS, u3, u1, SS, DD, SS, SS, SS, DD,
                                            bAdj, bAct, bAct, u2, DD, bAct, nullptr);
        gemm_k<2><<<gWmm, 512, 0, stream>>>(u1, WT + DD * DD, hout, BATCH * SS, DD, DD, DD, DD, DD,
                                            0, 0, 0, bias + DD, 0, 0, rden);
    }

    // t1 = [h1|1]*U  -> fp16 [8192][576] (col 512 carries the y-side bias term)
    gemm_k<3><<<gT1, 512, 0, stream>>>(u4, UT, t1h, BATCH * SS, 576, DD, DD, DD, 576,
                                       0, 0, 0, Ubias, 0, 0, nullptr);
    // score[b,x,y] = t1[b,x,:512].h2[b,y,:512] + t1[b,x,512]
    gemm_k<4><<<gSc, 512, 0, stream>>>(t1h, u2, out, SS, SS, DD, 576, DD, SS,
                                       (long)SS * 576, bAct, (long)SS * SS,
                                       t1h + 512, 576, (long)SS * 576, nullptr);
}

// Round 5
// 192.510 us; speedup vs baseline: 1.2002x; 1.2002x over previous
//
#include <hip/hip_runtime.h>

#define SS 1024
#define DD 512
#define BATCH 8
#define MIN_T 0.1f
#define MAX_T 0.9f

using half8  = __attribute__((ext_vector_type(8))) _Float16;
using floatx4 = __attribute__((ext_vector_type(4))) float;

typedef const __attribute__((address_space(1))) void gvoid;
typedef __attribute__((address_space(3))) void lvoid;

// ---------------- row-sum of pruned fp16 matrix -> rden = 1/(sum+1) ----------------
__global__ void rsum_k(const _Float16* __restrict__ A, float* __restrict__ rden, int rows) {
    int row = blockIdx.x * 4 + (threadIdx.x >> 6);
    if (row >= rows) return;
    int lane = threadIdx.x & 63;
    const _Float16* a = A + (size_t)row * SS;
    float s = 0.f;
#pragma unroll
    for (int r = 0; r < 2; ++r) {
        half8 v = *(const half8*)&a[(lane + 64 * r) * 8];
#pragma unroll
        for (int j = 0; j < 8; ++j) s += (float)v[j];
    }
#pragma unroll
    for (int m = 32; m > 0; m >>= 1) s += __shfl_xor(s, m, 64);
    if (lane == 0) rden[row] = 1.0f / (s + 1.0f);
}

// ---------------- generic cast / prune / transpose prep ----------------
template <typename ST, bool PRUNE, bool DON, bool DOT>
__global__ void prep_k(const ST* __restrict__ src, int sld, long bS,
                       _Float16* __restrict__ dN, int ldN, long bN,
                       _Float16* __restrict__ dT, int ldT, long bT,
                       int srcR, int srcC, int dTR, int dTC) {
    __shared__ float lt[64][65];
    src += (size_t)blockIdx.z * bS;
    int c0 = blockIdx.x * 64, r0 = blockIdx.y * 64;
    int tx = threadIdx.x, ty = threadIdx.y;  // 64 x 4
#pragma unroll
    for (int it = 0; it < 16; ++it) {
        int r = r0 + ty + it * 4, c = c0 + tx;
        float v = 0.f;
        if (r < srcR && c < srcC) v = (float)src[(size_t)r * sld + c];
        if (PRUNE) v = (v >= MIN_T && v <= MAX_T) ? v : 0.f;
        if (DON) {
            if (r < srcR && c < srcC)
                dN[(size_t)blockIdx.z * bN + (size_t)r * ldN + c] = (_Float16)v;
        }
        if (DOT) lt[tx][ty + it * 4] = v;
    }
    if (DOT) {
        __syncthreads();
#pragma unroll
        for (int it = 0; it < 16; ++it) {
            int tr = c0 + ty + it * 4, tc = r0 + tx;
            if (tr < dTR && tc < dTC)
                dT[(size_t)blockIdx.z * bT + (size_t)tr * ldT + tc] =
                    (_Float16)lt[ty + it * 4][tx];
        }
    }
}

__global__ void ubias_k(const float* __restrict__ U, float* __restrict__ ub) {
    int n = blockIdx.x * 64 + threadIdx.x;
    if (n < 576) ub[n] = (n < 513) ? U[512 * 513 + n] : 0.f;
}

// ---------------- MFMA GEMM: C = A[M][K] * B[N][K]^T, fp16 in / fp32 acc ----------------
// 128x128 tile, 512 threads = 8 waves (2x4), 64x32 per wave.
// z-batch: A += z*bA, B += (z&zmB)*bB, C += z*bC, e0 += (z&zmE)*bE0.
// EPI: 1 = agg + fp16X add (C fp16)
//      2 = wmm relu((acc + e0f[n]) * e1[m]) (C fp16)
//      3 = t1 acc+e0f[n], store guard n<N (C fp16)
//      4 = score acc+(float)e0h[m*e0ld] (C fp32)
constexpr int GBM = 128, GBN = 128, GBK = 64;

template <int EPI>
__global__ __launch_bounds__(512, 4) void gemm_k(
    const _Float16* __restrict__ A, const _Float16* __restrict__ B, void* __restrict__ Cv,
    int M, int N, int K, int lda, int ldb, int ldc,
    long bA, long bB, long bC, int zmB,
    const void* __restrict__ e0, int e0ld, long bE0, int zmE,
    const float* __restrict__ e1) {
    __shared__ _Float16 lA[2][GBM * GBK];  // [128][64], 8x16B chunks/row, source-swizzled
    __shared__ _Float16 lB[2][GBN * GBK];  // [128][64]

    const int z = blockIdx.z;
    A += (size_t)z * bA;
    B += (size_t)(z & zmB) * bB;
    const int m0 = blockIdx.x * GBM, n0 = blockIdx.y * GBN;
    const int tid = threadIdx.x;
    const int lane = tid & 63, wv = tid >> 6;
    const int wr = wv >> 2, wc = wv & 3;  // 2x4 waves, 64x32 per wave

    auto stage = [&](int buf, int kt) {
#pragma unroll
        for (int it = 0; it < 2; ++it) {  // A: 1024 chunks
            int q = it * 512 + tid;
            int r = q >> 3, cp = q & 7, cl = cp ^ (r & 7);
            const _Float16* g = A + (size_t)(m0 + r) * lda + kt + cl * 8;
            __builtin_amdgcn_global_load_lds((gvoid*)g,
                (lvoid*)(&lA[buf][(it * 512 + wv * 64) * 8]), 16, 0, 0);
        }
#pragma unroll
        for (int it = 0; it < 2; ++it) {  // B: 1024 chunks
            int q = it * 512 + tid;
            int r = q >> 3, cp = q & 7, cl = cp ^ (r & 7);
            const _Float16* g = B + (size_t)(n0 + r) * ldb + kt + cl * 8;
            __builtin_amdgcn_global_load_lds((gvoid*)g,
                (lvoid*)(&lB[buf][(it * 512 + wv * 64) * 8]), 16, 0, 0);
        }
    };

    floatx4 acc[4][2] = {};

    stage(0, 0);
    asm volatile("s_waitcnt vmcnt(0)");
    __syncthreads();
    int cur = 0;
    for (int kt = 0; kt < K; kt += GBK) {
        int nxt = kt + GBK;
        if (nxt < K) stage(cur ^ 1, nxt);
#pragma unroll
        for (int kk = 0; kk < 2; ++kk) {
            half8 af[4], bf[2];
#pragma unroll
            for (int i = 0; i < 4; ++i) {
                int row = wr * 64 + i * 16 + (lane & 15);
                int cl = kk * 4 + (lane >> 4);
                int cp = cl ^ (row & 7);
                af[i] = *(const half8*)&lA[cur][row * 64 + cp * 8];
            }
#pragma unroll
            for (int j = 0; j < 2; ++j) {
                int row = wc * 32 + j * 16 + (lane & 15);
                int cl = kk * 4 + (lane >> 4);
                int cp = cl ^ (row & 7);
                bf[j] = *(const half8*)&lB[cur][row * 64 + cp * 8];
            }
#pragma unroll
            for (int i = 0; i < 4; ++i)
#pragma unroll
                for (int j = 0; j < 2; ++j)
                    acc[i][j] = __builtin_amdgcn_mfma_f32_16x16x32_f16(af[i], bf[j], acc[i][j], 0, 0, 0);
        }
        if (nxt < K) {
            asm volatile("s_waitcnt vmcnt(0)");
            __syncthreads();
        }
        cur ^= 1;
    }

    // epilogue: C map col=lane&15, row=(lane>>4)*4+r
    const int cm = (lane >> 4) * 4;
    const int cn = lane & 15;
#pragma unroll
    for (int i = 0; i < 4; ++i) {
#pragma unroll
        for (int j = 0; j < 2; ++j) {
#pragma unroll
            for (int r = 0; r < 4; ++r) {
                int m = m0 + wr * 64 + i * 16 + cm + r;
                int n = n0 + wc * 32 + j * 16 + cn;
                float v = acc[i][j][r];
                if constexpr (EPI == 1) {
                    const _Float16* X = (const _Float16*)e0 + (size_t)(z & zmE) * bE0;
                    v += (float)X[(size_t)m * e0ld + n];
                    ((_Float16*)Cv)[(size_t)z * bC + (size_t)m * ldc + n] = (_Float16)v;
                } else if constexpr (EPI == 2) {
                    v = (v + ((const float*)e0)[n]) * e1[m];
                    v = v > 0.f ? v : 0.f;
                    ((_Float16*)Cv)[(size_t)z * bC + (size_t)m * ldc + n] = (_Float16)v;
                } else if constexpr (EPI == 3) {
                    if (n < N) {
                        v += ((const float*)e0)[n];
                        ((_Float16*)Cv)[(size_t)z * bC + (size_t)m * ldc + n] = (_Float16)v;
                    }
                } else {
                    const _Float16* tb = (const _Float16*)e0 + (size_t)(z & zmE) * bE0;
                    v += (float)tb[(size_t)m * e0ld];
                    ((float*)Cv)[(size_t)z * bC + (size_t)m * ldc + n] = v;
                }
            }
        }
    }
}

extern "C" void kernel_launch(void* const* d_in, const int* in_sizes, int n_in,
                              void* d_out, int out_size, void* d_ws, size_t ws_size,
                              hipStream_t stream) {
    const float* x0  = (const float*)d_in[0];  // [B,S,D]
    const float* adj = (const float*)d_in[1];  // [B,S,S]
    const float* W1  = (const float*)d_in[2];  // [L,D,D]
    const float* b1  = (const float*)d_in[3];  // [L,D]
    const float* W2  = (const float*)d_in[4];
    const float* b2  = (const float*)d_in[5];
    const float* U   = (const float*)d_in[6];  // [1,513,513]
    float* out = (float*)d_out;

    char* ws = (char*)d_ws;
    const size_t MB = 1u << 20;
    const long bAdj = (long)SS * SS, bAct = (long)SS * DD;
    _Float16* adjcat = (_Float16*)(ws);            // 32 MB: 16 mats (8 natural, 8 transposed)
    _Float16* x0t  = (_Float16*)(ws + 32 * MB);    // 8 MB x0^T fp16
    _Float16* x0h  = (_Float16*)(ws + 40 * MB);    // 8 MB x0 fp16 natural
    _Float16* u1   = (_Float16*)(ws + 48 * MB);    // 16 MB Y (both streams)
    _Float16* u2   = (_Float16*)(ws + 64 * MB);    // 16 MB X' (both streams)
    _Float16* u3   = (_Float16*)(ws + 80 * MB);    // 16 MB X'^T (both streams)
    _Float16* h12  = (_Float16*)(ws + 96 * MB);    // 16 MB h1 (z 0-7) + h2 (z 8-15)
    _Float16* t1h  = (_Float16*)(ws + 112 * MB);   // [8192][576] 9.44 MB
    _Float16* W1T  = (_Float16*)(ws + 122 * MB);   // 1 MB
    _Float16* W2T  = (_Float16*)(ws + 123 * MB);   // 1 MB
    _Float16* UT   = (_Float16*)(ws + 124 * MB);   // [640][512] zero-padded
    float* Ubias   = (float*)(ws + 125 * MB);
    float* rden12  = (float*)(ws + 125 * MB + 16384);  // [16384]

    dim3 tb(64, 4);
    prep_k<float, false, false, true><<<dim3(8, 8, 2), tb, 0, stream>>>(
        W1, DD, (long)DD * DD, nullptr, 0, 0, W1T, DD, (long)DD * DD, DD, DD, DD, DD);
    prep_k<float, false, false, true><<<dim3(8, 8, 2), tb, 0, stream>>>(
        W2, DD, (long)DD * DD, nullptr, 0, 0, W2T, DD, (long)DD * DD, DD, DD, DD, DD);
    prep_k<float, false, false, true><<<dim3(10, 8, 1), tb, 0, stream>>>(
        U, 513, 0, nullptr, 0, 0, UT, DD, 0, 512, 513, 640, 512);
    ubias_k<<<9, 64, 0, stream>>>(U, Ubias);
    prep_k<float, false, true, true><<<dim3(8, 16, BATCH), tb, 0, stream>>>(
        x0, DD, bAct, x0h, DD, bAct, x0t, SS, bAct, SS, DD, DD, SS);
    // pruned adjacency: natural (z 0-7) + transposed (z 8-15) in ONE fp32 pass
    prep_k<float, true, true, true><<<dim3(16, 16, BATCH), tb, 0, stream>>>(
        adj, SS, bAdj, adjcat, SS, bAdj, adjcat + 8 * bAdj, SS, bAdj, SS, SS, SS, SS);
    // merged denominators: rows 0-8191 -> rden1, rows 8192-16383 -> rden2
    rsum_k<<<16384 / 4, 256, 0, stream>>>(adjcat, rden12, 16384);

    dim3 gAgg(SS / GBM, DD / GBN, 16);           // 512 blocks, 2/CU
    dim3 gWmm(BATCH * SS / GBM, DD / GBN, 1);    // 256 blocks (per stream)
    dim3 gT1(BATCH * SS / GBM, 5, 1);            // (64,5), N padded to 640
    dim3 gSc(SS / GBM, SS / GBN, BATCH);         // 512 blocks

    // layer 0 aggregation, both streams in one dispatch (z = stream*8 + batch)
    gemm_k<1><<<gAgg, 512, 0, stream>>>(adjcat, x0t, u1, SS, DD, SS, SS, SS, DD,
                                        bAdj, bAct, bAct, 7, x0h, DD, bAct, 7, nullptr);
    // layer 0 transform (weights differ per stream -> two dispatches)
    gemm_k<2><<<gWmm, 512, 0, stream>>>(u1, W1T, u2, BATCH * SS, DD, DD, DD, DD, DD,
                                        0, 0, 0, 0, b1, 0, 0, 0, rden12);
    gemm_k<2><<<gWmm, 512, 0, stream>>>(u1 + 8 * bAct, W2T, u2 + 8 * bAct,
                                        BATCH * SS, DD, DD, DD, DD, DD,
                                        0, 0, 0, 0, b2, 0, 0, 0, rden12 + 8192);
    // transpose activations (both streams)
    prep_k<_Float16, false, false, true><<<dim3(8, 16, 16), tb, 0, stream>>>(
        u2, DD, bAct, nullptr, 0, 0, u3, SS, bAct, SS, DD, DD, SS);
    // layer 1 aggregation
    gemm_k<1><<<gAgg, 512, 0, stream>>>(adjcat, u3, u1, SS, DD, SS, SS, SS, DD,
                                        bAdj, bAct, bAct, 15, u2, DD, bAct, 15, nullptr);
    // layer 1 transform -> h1 (z 0-7 region) / h2 (z 8-15 region)
    gemm_k<2><<<gWmm, 512, 0, stream>>>(u1, W1T + DD * DD, h12, BATCH * SS, DD, DD, DD, DD, DD,
                                        0, 0, 0, 0, b1 + DD, 0, 0, 0, rden12);
    gemm_k<2><<<gWmm, 512, 0, stream>>>(u1 + 8 * bAct, W2T + DD * DD, h12 + 8 * bAct,
                                        BATCH * SS, DD, DD, DD, DD, DD,
                                        0, 0, 0, 0, b2 + DD, 0, 0, 0, rden12 + 8192);

    // t1 = [h1|1]*U
    gemm_k<3><<<gT1, 512, 0, stream>>>(h12, UT, t1h, BATCH * SS, 576, DD, DD, DD, 576,
                                       0, 0, 0, 0, Ubias, 0, 0, 0, nullptr);
    // score[b,x,y] = t1[b,x,:512].h2[b,y,:512] + t1[b,x,512]
    gemm_k<4><<<gSc, 512, 0, stream>>>(t1h, h12 + 8 * bAct, out, SS, SS, DD, 576, DD, SS,
                                       (long)SS * 576, bAct, (long)SS * SS, 15,
                                       t1h + 512, 576, (long)SS * 576, 15, nullptr);
}

// Round 7
// 179.873 us; speedup vs baseline: 1.2846x; 1.0703x over previous
//
#include <hip/hip_runtime.h>

#define SS 1024
#define DD 512
#define BATCH 8
#define MIN_T 0.1f
#define MAX_T 0.9f

using half8  = __attribute__((ext_vector_type(8))) _Float16;
using floatx4 = __attribute__((ext_vector_type(4))) float;

typedef const __attribute__((address_space(1))) void gvoid;
typedef __attribute__((address_space(3))) void lvoid;

// ---------------- row-sum of pruned fp16 matrix -> rden = 1/(sum+1) ----------------
__global__ void rsum_k(const _Float16* __restrict__ A, float* __restrict__ rden, int rows) {
    int row = blockIdx.x * 4 + (threadIdx.x >> 6);
    if (row >= rows) return;
    int lane = threadIdx.x & 63;
    const _Float16* a = A + (size_t)row * SS;
    float s = 0.f;
#pragma unroll
    for (int r = 0; r < 2; ++r) {
        half8 v = *(const half8*)&a[(lane + 64 * r) * 8];
#pragma unroll
        for (int j = 0; j < 8; ++j) s += (float)v[j];
    }
#pragma unroll
    for (int m = 32; m > 0; m >>= 1) s += __shfl_xor(s, m, 64);
    if (lane == 0) rden[row] = 1.0f / (s + 1.0f);
}

// ---------------- generic cast / prune / transpose prep ----------------
template <typename ST, bool PRUNE, bool DON, bool DOT>
__global__ void prep_k(const ST* __restrict__ src, int sld, long bS,
                       _Float16* __restrict__ dN, int ldN, long bN,
                       _Float16* __restrict__ dT, int ldT, long bT,
                       int srcR, int srcC, int dTR, int dTC) {
    __shared__ float lt[64][65];
    src += (size_t)blockIdx.z * bS;
    int c0 = blockIdx.x * 64, r0 = blockIdx.y * 64;
    int tx = threadIdx.x, ty = threadIdx.y;  // 64 x 4
#pragma unroll
    for (int it = 0; it < 16; ++it) {
        int r = r0 + ty + it * 4, c = c0 + tx;
        float v = 0.f;
        if (r < srcR && c < srcC) v = (float)src[(size_t)r * sld + c];
        if (PRUNE) v = (v >= MIN_T && v <= MAX_T) ? v : 0.f;
        if (DON) {
            if (r < srcR && c < srcC)
                dN[(size_t)blockIdx.z * bN + (size_t)r * ldN + c] = (_Float16)v;
        }
        if (DOT) lt[tx][ty + it * 4] = v;
    }
    if (DOT) {
        __syncthreads();
#pragma unroll
        for (int it = 0; it < 16; ++it) {
            int tr = c0 + ty + it * 4, tc = r0 + tx;
            if (tr < dTR && tc < dTC)
                dT[(size_t)blockIdx.z * bT + (size_t)tr * ldT + tc] =
                    (_Float16)lt[ty + it * 4][tx];
        }
    }
}

// ---------------- pack U-bias row (576) + bias concat bcat[2][2][512] ----------------
__global__ void bias_k(const float* __restrict__ U, const float* __restrict__ b1,
                       const float* __restrict__ b2, float* __restrict__ ub,
                       float* __restrict__ bcat) {
    int i = blockIdx.x * 256 + threadIdx.x;
    if (i < 576) ub[i] = (i < 513) ? U[512 * 513 + i] : 0.f;
    if (i < 2048) {
        int l = i >> 10, st = (i >> 9) & 1, n = i & 511;
        bcat[i] = (st == 0) ? b1[l * 512 + n] : b2[l * 512 + n];
    }
}

// ---------------- MFMA GEMM: C = A[M][K] * B[N][K]^T, fp16 in / fp32 acc ----------------
// 128x128 tile, 512 threads = 8 waves (2x4), 64x32 per wave.
// z-batch: A += z*bA, B += (z&zmB)*bB, C += z*bC.
// EPI: 1 = agg + fp16X add (C fp16), X = e0 + (z&zmE)*bE0, stride e0ld
//      2 = wmm relu((acc + bias[n]) * rden[m]) (C fp16); bias = e0 + (z&zmE)*bE0,
//          rden = e1 + z*e0ld  (e0ld doubles as rden z-stride)
//      5 = EPI2 + ALSO store transposed into Cv2: [(z*8 + (m>>10))*bAct + n*SS + (m&1023)]
//      3 = t1 acc + e0f[n], store guard n<N (C fp16)
//      4 = score acc + (float)e0h[m*e0ld] (C fp32), e0 += (z&zmE)*bE0
constexpr int GBM = 128, GBN = 128, GBK = 64;

template <int EPI>
__global__ __launch_bounds__(512, 4) void gemm_k(
    const _Float16* __restrict__ A, const _Float16* __restrict__ B, void* __restrict__ Cv,
    void* __restrict__ Cv2,
    int M, int N, int K, int lda, int ldb, int ldc,
    long bA, long bB, long bC, int zmB,
    const void* __restrict__ e0, int e0ld, long bE0, int zmE,
    const float* __restrict__ e1) {
    __shared__ _Float16 lA[2][GBM * GBK];  // [128][64], 8x16B chunks/row, source-swizzled
    __shared__ _Float16 lB[2][GBN * GBK];  // [128][64]

    const int z = blockIdx.z;
    A += (size_t)z * bA;
    B += (size_t)(z & zmB) * bB;
    const int m0 = blockIdx.x * GBM, n0 = blockIdx.y * GBN;
    const int tid = threadIdx.x;
    const int lane = tid & 63, wv = tid >> 6;
    const int wr = wv >> 2, wc = wv & 3;  // 2x4 waves, 64x32 per wave

    auto stage = [&](int buf, int kt) {
#pragma unroll
        for (int it = 0; it < 2; ++it) {  // A: 1024 chunks
            int q = it * 512 + tid;
            int r = q >> 3, cp = q & 7, cl = cp ^ (r & 7);
            const _Float16* g = A + (size_t)(m0 + r) * lda + kt + cl * 8;
            __builtin_amdgcn_global_load_lds((gvoid*)g,
                (lvoid*)(&lA[buf][(it * 512 + wv * 64) * 8]), 16, 0, 0);
        }
#pragma unroll
        for (int it = 0; it < 2; ++it) {  // B: 1024 chunks
            int q = it * 512 + tid;
            int r = q >> 3, cp = q & 7, cl = cp ^ (r & 7);
            const _Float16* g = B + (size_t)(n0 + r) * ldb + kt + cl * 8;
            __builtin_amdgcn_global_load_lds((gvoid*)g,
                (lvoid*)(&lB[buf][(it * 512 + wv * 64) * 8]), 16, 0, 0);
        }
    };

    floatx4 acc[4][2] = {};

    stage(0, 0);
    asm volatile("s_waitcnt vmcnt(0)");
    __syncthreads();
    int cur = 0;
    for (int kt = 0; kt < K; kt += GBK) {
        int nxt = kt + GBK;
        if (nxt < K) stage(cur ^ 1, nxt);
#pragma unroll
        for (int kk = 0; kk < 2; ++kk) {
            half8 af[4], bf[2];
#pragma unroll
            for (int i = 0; i < 4; ++i) {
                int row = wr * 64 + i * 16 + (lane & 15);
                int cl = kk * 4 + (lane >> 4);
                int cp = cl ^ (row & 7);
                af[i] = *(const half8*)&lA[cur][row * 64 + cp * 8];
            }
#pragma unroll
            for (int j = 0; j < 2; ++j) {
                int row = wc * 32 + j * 16 + (lane & 15);
                int cl = kk * 4 + (lane >> 4);
                int cp = cl ^ (row & 7);
                bf[j] = *(const half8*)&lB[cur][row * 64 + cp * 8];
            }
#pragma unroll
            for (int i = 0; i < 4; ++i)
#pragma unroll
                for (int j = 0; j < 2; ++j)
                    acc[i][j] = __builtin_amdgcn_mfma_f32_16x16x32_f16(af[i], bf[j], acc[i][j], 0, 0, 0);
        }
        if (nxt < K) {
            asm volatile("s_waitcnt vmcnt(0)");
            __syncthreads();
        }
        cur ^= 1;
    }

    // epilogue: C map col=lane&15, row=(lane>>4)*4+r
    const int cm = (lane >> 4) * 4;
    const int cn = lane & 15;
    const long bAct = (long)SS * DD;
#pragma unroll
    for (int i = 0; i < 4; ++i) {
#pragma unroll
        for (int j = 0; j < 2; ++j) {
#pragma unroll
            for (int r = 0; r < 4; ++r) {
                int m = m0 + wr * 64 + i * 16 + cm + r;
                int n = n0 + wc * 32 + j * 16 + cn;
                float v = acc[i][j][r];
                if constexpr (EPI == 1) {
                    const _Float16* X = (const _Float16*)e0 + (size_t)(z & zmE) * bE0;
                    v += (float)X[(size_t)m * e0ld + n];
                    ((_Float16*)Cv)[(size_t)z * bC + (size_t)m * ldc + n] = (_Float16)v;
                } else if constexpr (EPI == 2 || EPI == 5) {
                    const float* bb = (const float*)e0 + (size_t)(z & zmE) * bE0;
                    v = (v + bb[n]) * e1[(size_t)z * e0ld + m];
                    v = v > 0.f ? v : 0.f;
                    ((_Float16*)Cv)[(size_t)z * bC + (size_t)m * ldc + n] = (_Float16)v;
                    if constexpr (EPI == 5) {
                        int bt = m >> 10, s = m & 1023;
                        ((_Float16*)Cv2)[(size_t)(z * 8 + bt) * bAct + (size_t)n * SS + s] =
                            (_Float16)v;
                    }
                } else if constexpr (EPI == 3) {
                    if (n < N) {
                        v += ((const float*)e0)[n];
                        ((_Float16*)Cv)[(size_t)z * bC + (size_t)m * ldc + n] = (_Float16)v;
                    }
                } else {
                    const _Float16* tb = (const _Float16*)e0 + (size_t)(z & zmE) * bE0;
                    v += (float)tb[(size_t)m * e0ld];
                    ((float*)Cv)[(size_t)z * bC + (size_t)m * ldc + n] = v;
                }
            }
        }
    }
}

extern "C" void kernel_launch(void* const* d_in, const int* in_sizes, int n_in,
                              void* d_out, int out_size, void* d_ws, size_t ws_size,
                              hipStream_t stream) {
    const float* x0  = (const float*)d_in[0];  // [B,S,D]
    const float* adj = (const float*)d_in[1];  // [B,S,S]
    const float* W1  = (const float*)d_in[2];  // [L,D,D]
    const float* b1  = (const float*)d_in[3];  // [L,D]
    const float* W2  = (const float*)d_in[4];
    const float* b2  = (const float*)d_in[5];
    const float* U   = (const float*)d_in[6];  // [1,513,513]
    float* out = (float*)d_out;

    char* ws = (char*)d_ws;
    const size_t MB = 1u << 20;
    const long bAdj = (long)SS * SS, bAct = (long)SS * DD;
    const long DD2 = (long)DD * DD;
    _Float16* adjcat = (_Float16*)(ws);            // 32 MB: 16 mats (8 natural, 8 transposed)
    _Float16* x0t  = (_Float16*)(ws + 32 * MB);    // 8 MB x0^T fp16
    _Float16* x0h  = (_Float16*)(ws + 40 * MB);    // 8 MB x0 fp16 natural
    _Float16* u1   = (_Float16*)(ws + 48 * MB);    // 16 MB Y (both streams)
    _Float16* u2   = (_Float16*)(ws + 64 * MB);    // 16 MB X' natural (both streams)
    _Float16* u3   = (_Float16*)(ws + 80 * MB);    // 16 MB X'^T (both streams)
    _Float16* h12  = (_Float16*)(ws + 96 * MB);    // 16 MB h1 (z 0-7) + h2 (z 8-15)
    _Float16* t1h  = (_Float16*)(ws + 112 * MB);   // [8192][576] 9.44 MB
    _Float16* Wcat = (_Float16*)(ws + 122 * MB);   // [2 layer][2 stream][512][512] = 2 MB (122-124)
    _Float16* UT   = (_Float16*)(ws + 124 * MB);   // [640][512] zero-padded, 0.64 MB
    float* Ubias   = (float*)(ws + 125 * MB);          // [576]
    float* bcat    = (float*)(ws + 125 * MB + 4096);   // [2][2][512]
    float* rden12  = (float*)(ws + 125 * MB + 16384);  // [16384]

    dim3 tb(64, 4);
    // weight preps: Wcat[l][0] = W1[l]^T, Wcat[l][1] = W2[l]^T
    prep_k<float, false, false, true><<<dim3(8, 8, 2), tb, 0, stream>>>(
        W1, DD, DD2, nullptr, 0, 0, Wcat, DD, 2 * DD2, DD, DD, DD, DD);
    prep_k<float, false, false, true><<<dim3(8, 8, 2), tb, 0, stream>>>(
        W2, DD, DD2, nullptr, 0, 0, Wcat + DD2, DD, 2 * DD2, DD, DD, DD, DD);
    prep_k<float, false, false, true><<<dim3(10, 8, 1), tb, 0, stream>>>(
        U, 513, 0, nullptr, 0, 0, UT, DD, 0, 512, 513, 640, 512);
    bias_k<<<8, 256, 0, stream>>>(U, b1, b2, Ubias, bcat);
    prep_k<float, false, true, true><<<dim3(8, 16, BATCH), tb, 0, stream>>>(
        x0, DD, bAct, x0h, DD, bAct, x0t, SS, bAct, SS, DD, DD, SS);
    // pruned adjacency: natural (z 0-7) + transposed (z 8-15) in ONE fp32 pass
    prep_k<float, true, true, true><<<dim3(16, 16, BATCH), tb, 0, stream>>>(
        adj, SS, bAdj, adjcat, SS, bAdj, adjcat + 8 * bAdj, SS, bAdj, SS, SS, SS, SS);
    // merged denominators: rows 0-8191 -> rden1, rows 8192-16383 -> rden2
    rsum_k<<<16384 / 4, 256, 0, stream>>>(adjcat, rden12, 16384);

    dim3 gAgg(SS / GBM, DD / GBN, 16);           // 512 blocks, 2/CU
    dim3 gWmm(BATCH * SS / GBM, DD / GBN, 2);    // 512 blocks (both streams)
    dim3 gT1(BATCH * SS / GBM, 5, 1);            // (64,5), N padded to 640
    dim3 gSc(SS / GBM, SS / GBN, BATCH);         // 512 blocks

    // layer 0 aggregation, both streams (z = stream*8 + batch)
    gemm_k<1><<<gAgg, 512, 0, stream>>>(adjcat, x0t, u1, nullptr, SS, DD, SS, SS, SS, DD,
                                        bAdj, bAct, bAct, 7, x0h, DD, bAct, 7, nullptr);
    // layer 0 transform, both streams in one z=2 dispatch; epilogue also writes X'^T -> u3
    gemm_k<5><<<gWmm, 512, 0, stream>>>(u1, Wcat, u2, u3, BATCH * SS, DD, DD, DD, DD, DD,
                                        8 * bAct, DD2, 8 * bAct, 1,
                                        bcat, 8192, 512, 1, rden12);
    // layer 1 aggregation (B = X'^T, self-loop add = X' natural)
    gemm_k<1><<<gAgg, 512, 0, stream>>>(adjcat, u3, u1, nullptr, SS, DD, SS, SS, SS, DD,
                                        bAdj, bAct, bAct, 15, u2, DD, bAct, 15, nullptr);
    // layer 1 transform -> h1 (z=0) / h2 (z=1)
    gemm_k<2><<<gWmm, 512, 0, stream>>>(u1, Wcat + 2 * DD2, h12, nullptr,
                                        BATCH * SS, DD, DD, DD, DD, DD,
                                        8 * bAct, DD2, 8 * bAct, 1,
                                        bcat + 1024, 8192, 512, 1, rden12);

    // t1 = [h1|1]*U
    gemm_k<3><<<gT1, 512, 0, stream>>>(h12, UT, t1h, nullptr, BATCH * SS, 576, DD, DD, DD, 576,
                                       0, 0, 0, 0, Ubias, 0, 0, 0, nullptr);
    // score[b,x,y] = t1[b,x,:512].h2[b,y,:512] + t1[b,x,512]
    gemm_k<4><<<gSc, 512, 0, stream>>>(t1h, h12 + 8 * bAct, out, nullptr, SS, SS, DD, 576, DD, SS,
                                       (long)SS * 576, bAct, (long)SS * SS, 15,
                                       t1h + 512, 576, (long)SS * 576, 15, nullptr);
}

// Round 8
// 168.372 us; speedup vs baseline: 1.3723x; 1.0683x over previous
//
#include <hip/hip_runtime.h>

#define SS 1024
#define DD 512
#define BATCH 8
#define MIN_T 0.1f
#define MAX_T 0.9f

using half8  = __attribute__((ext_vector_type(8))) _Float16;
using floatx4 = __attribute__((ext_vector_type(4))) float;

typedef const __attribute__((address_space(1))) void gvoid;
typedef __attribute__((address_space(3))) void lvoid;

// ---------------- row-sum of pruned fp16 matrix -> rden = 1/(sum+1) ----------------
__global__ void rsum_k(const _Float16* __restrict__ A, float* __restrict__ rden, int rows) {
    int row = blockIdx.x * 4 + (threadIdx.x >> 6);
    if (row >= rows) return;
    int lane = threadIdx.x & 63;
    const _Float16* a = A + (size_t)row * SS;
    float s = 0.f;
#pragma unroll
    for (int r = 0; r < 2; ++r) {
        half8 v = *(const half8*)&a[(lane + 64 * r) * 8];
#pragma unroll
        for (int j = 0; j < 8; ++j) s += (float)v[j];
    }
#pragma unroll
    for (int m = 32; m > 0; m >>= 1) s += __shfl_xor(s, m, 64);
    if (lane == 0) rden[row] = 1.0f / (s + 1.0f);
}

// ---------------- generic cast / prune / transpose prep ----------------
template <typename ST, bool PRUNE, bool DON, bool DOT>
__global__ void prep_k(const ST* __restrict__ src, int sld, long bS,
                       _Float16* __restrict__ dN, int ldN, long bN,
                       _Float16* __restrict__ dT, int ldT, long bT,
                       int srcR, int srcC, int dTR, int dTC) {
    __shared__ float lt[64][65];
    src += (size_t)blockIdx.z * bS;
    int c0 = blockIdx.x * 64, r0 = blockIdx.y * 64;
    int tx = threadIdx.x, ty = threadIdx.y;  // 64 x 4
#pragma unroll
    for (int it = 0; it < 16; ++it) {
        int r = r0 + ty + it * 4, c = c0 + tx;
        float v = 0.f;
        if (r < srcR && c < srcC) v = (float)src[(size_t)r * sld + c];
        if (PRUNE) v = (v >= MIN_T && v <= MAX_T) ? v : 0.f;
        if (DON) {
            if (r < srcR && c < srcC)
                dN[(size_t)blockIdx.z * bN + (size_t)r * ldN + c] = (_Float16)v;
        }
        if (DOT) lt[tx][ty + it * 4] = v;
    }
    if (DOT) {
        __syncthreads();
#pragma unroll
        for (int it = 0; it < 16; ++it) {
            int tr = c0 + ty + it * 4, tc = r0 + tx;
            if (tr < dTR && tc < dTC)
                dT[(size_t)blockIdx.z * bT + (size_t)tr * ldT + tc] =
                    (_Float16)lt[ty + it * 4][tx];
        }
    }
}

// ---------------- fused small preps: z 0-3 = Wcat[l][st] = W{1,2}[l]^T, z=4 = UT + bias pack ----------------
__global__ void wprep_k(const float* __restrict__ W1, const float* __restrict__ W2,
                        const float* __restrict__ U, const float* __restrict__ b1,
                        const float* __restrict__ b2, _Float16* __restrict__ Wcat,
                        _Float16* __restrict__ UT, float* __restrict__ Ubias,
                        float* __restrict__ bcat) {
    __shared__ float lt[64][65];
    const int z = blockIdx.z;
    const float* src;
    _Float16* dT;
    int sld, srcR, srcC, dTR, dTC, ldT;
    if (z < 4) {
        int l = z >> 1, st = z & 1;
        src = (st ? W2 : W1) + (size_t)l * DD * DD;
        sld = DD; srcR = DD; srcC = DD;
        dT = Wcat + (size_t)z * DD * DD; ldT = DD; dTR = DD; dTC = DD;
    } else {
        src = U; sld = 513; srcR = 512; srcC = 513;
        dT = UT; ldT = DD; dTR = 640; dTC = DD;
    }
    int c0 = blockIdx.x * 64, r0 = blockIdx.y * 64;
    int tx = threadIdx.x, ty = threadIdx.y;  // 64 x 4
#pragma unroll
    for (int it = 0; it < 16; ++it) {
        int r = r0 + ty + it * 4, c = c0 + tx;
        float v = 0.f;
        if (r < srcR && c < srcC) v = src[(size_t)r * sld + c];
        lt[tx][ty + it * 4] = v;
    }
    __syncthreads();
#pragma unroll
    for (int it = 0; it < 16; ++it) {
        int tr = c0 + ty + it * 4, tc = r0 + tx;
        if (tr < dTR && tc < dTC)
            dT[(size_t)tr * ldT + tc] = (_Float16)lt[ty + it * 4][tx];
    }
    if (z == 4 && blockIdx.x == 0 && blockIdx.y == 0) {
        int tid = ty * 64 + tx;
        for (int i = tid; i < 2048; i += 256) {
            int l = i >> 10, st = (i >> 9) & 1, n = i & 511;
            bcat[i] = (st == 0) ? b1[l * 512 + n] : b2[l * 512 + n];
        }
        for (int i = tid; i < 576; i += 256) Ubias[i] = (i < 513) ? U[512 * 513 + i] : 0.f;
    }
}

// ---------------- MFMA GEMM: C = A[M][K] * B[N][K]^T, fp16 in / fp32 acc ----------------
// 128x128 tile, 512 threads = 8 waves (2x4), 64x32 per wave.
// XCD-chunked block swizzle (grid size must be %8==0): consecutive work-ids
// (sharing B panels / per-z A matrices) land on the same XCD's L2.
// z-batch: A += z*bA, B += (z&zmB)*bB, C += z*bC.
// EPI: 1 = agg + fp16X add; 2 = wmm relu((acc+bias[n])*rden[m]);
//      5 = EPI2 + transposed store to Cv2; 3 = t1 acc+e0f[n], guard n<N;
//      4 = score acc+(float)e0h[m*e0ld] (C fp32)
constexpr int GBM = 128, GBN = 128, GBK = 64;

template <int EPI>
__global__ __launch_bounds__(512, 4) void gemm_k(
    const _Float16* __restrict__ A, const _Float16* __restrict__ B, void* __restrict__ Cv,
    void* __restrict__ Cv2,
    int M, int N, int K, int lda, int ldb, int ldc,
    long bA, long bB, long bC, int zmB,
    const void* __restrict__ e0, int e0ld, long bE0, int zmE,
    const float* __restrict__ e1) {
    __shared__ _Float16 lA[2][GBM * GBK];  // [128][64], 8x16B chunks/row, source-swizzled
    __shared__ _Float16 lB[2][GBN * GBK];  // [128][64]

    // XCD-chunked swizzle: dispatch slot orig (XCD = orig%8) executes work w so that
    // each XCD owns a contiguous chunk of work-ids (m204 bijective form, nwg%8==0).
    const int gx = gridDim.x, gy = gridDim.y;
    const int nwg = gx * gy * gridDim.z;
    const int orig = (blockIdx.z * gy + blockIdx.y) * gx + blockIdx.x;
    const int w = (orig & 7) * (nwg >> 3) + (orig >> 3);
    const int bx = w % gx;
    const int wt = w / gx;
    const int by = wt % gy;
    const int z = wt / gy;

    A += (size_t)z * bA;
    B += (size_t)(z & zmB) * bB;
    const int m0 = bx * GBM, n0 = by * GBN;
    const int tid = threadIdx.x;
    const int lane = tid & 63, wv = tid >> 6;
    const int wr = wv >> 2, wc = wv & 3;  // 2x4 waves, 64x32 per wave

    auto stage = [&](int buf, int kt) {
#pragma unroll
        for (int it = 0; it < 2; ++it) {  // A: 1024 chunks
            int q = it * 512 + tid;
            int r = q >> 3, cp = q & 7, cl = cp ^ (r & 7);
            const _Float16* g = A + (size_t)(m0 + r) * lda + kt + cl * 8;
            __builtin_amdgcn_global_load_lds((gvoid*)g,
                (lvoid*)(&lA[buf][(it * 512 + wv * 64) * 8]), 16, 0, 0);
        }
#pragma unroll
        for (int it = 0; it < 2; ++it) {  // B: 1024 chunks
            int q = it * 512 + tid;
            int r = q >> 3, cp = q & 7, cl = cp ^ (r & 7);
            const _Float16* g = B + (size_t)(n0 + r) * ldb + kt + cl * 8;
            __builtin_amdgcn_global_load_lds((gvoid*)g,
                (lvoid*)(&lB[buf][(it * 512 + wv * 64) * 8]), 16, 0, 0);
        }
    };

    floatx4 acc[4][2] = {};

    stage(0, 0);
    asm volatile("s_waitcnt vmcnt(0)");
    __syncthreads();
    int cur = 0;
    for (int kt = 0; kt < K; kt += GBK) {
        int nxt = kt + GBK;
        if (nxt < K) stage(cur ^ 1, nxt);
#pragma unroll
        for (int kk = 0; kk < 2; ++kk) {
            half8 af[4], bf[2];
#pragma unroll
            for (int i = 0; i < 4; ++i) {
                int row = wr * 64 + i * 16 + (lane & 15);
                int cl = kk * 4 + (lane >> 4);
                int cp = cl ^ (row & 7);
                af[i] = *(const half8*)&lA[cur][row * 64 + cp * 8];
            }
#pragma unroll
            for (int j = 0; j < 2; ++j) {
                int row = wc * 32 + j * 16 + (lane & 15);
                int cl = kk * 4 + (lane >> 4);
                int cp = cl ^ (row & 7);
                bf[j] = *(const half8*)&lB[cur][row * 64 + cp * 8];
            }
#pragma unroll
            for (int i = 0; i < 4; ++i)
#pragma unroll
                for (int j = 0; j < 2; ++j)
                    acc[i][j] = __builtin_amdgcn_mfma_f32_16x16x32_f16(af[i], bf[j], acc[i][j], 0, 0, 0);
        }
        if (nxt < K) {
            asm volatile("s_waitcnt vmcnt(0)");
            __syncthreads();
        }
        cur ^= 1;
    }

    // epilogue: C map col=lane&15, row=(lane>>4)*4+r
    const int cm = (lane >> 4) * 4;
    const int cn = lane & 15;
    const long bAct = (long)SS * DD;
#pragma unroll
    for (int i = 0; i < 4; ++i) {
#pragma unroll
        for (int j = 0; j < 2; ++j) {
#pragma unroll
            for (int r = 0; r < 4; ++r) {
                int m = m0 + wr * 64 + i * 16 + cm + r;
                int n = n0 + wc * 32 + j * 16 + cn;
                float v = acc[i][j][r];
                if constexpr (EPI == 1) {
                    const _Float16* X = (const _Float16*)e0 + (size_t)(z & zmE) * bE0;
                    v += (float)X[(size_t)m * e0ld + n];
                    ((_Float16*)Cv)[(size_t)z * bC + (size_t)m * ldc + n] = (_Float16)v;
                } else if constexpr (EPI == 2 || EPI == 5) {
                    const float* bb = (const float*)e0 + (size_t)(z & zmE) * bE0;
                    v = (v + bb[n]) * e1[(size_t)z * e0ld + m];
                    v = v > 0.f ? v : 0.f;
                    ((_Float16*)Cv)[(size_t)z * bC + (size_t)m * ldc + n] = (_Float16)v;
                    if constexpr (EPI == 5) {
                        int bt = m >> 10, s = m & 1023;
                        ((_Float16*)Cv2)[(size_t)(z * 8 + bt) * bAct + (size_t)n * SS + s] =
                            (_Float16)v;
                    }
                } else if constexpr (EPI == 3) {
                    if (n < N) {
                        v += ((const float*)e0)[n];
                        ((_Float16*)Cv)[(size_t)z * bC + (size_t)m * ldc + n] = (_Float16)v;
                    }
                } else {
                    const _Float16* tb = (const _Float16*)e0 + (size_t)(z & zmE) * bE0;
                    v += (float)tb[(size_t)m * e0ld];
                    ((float*)Cv)[(size_t)z * bC + (size_t)m * ldc + n] = v;
                }
            }
        }
    }
}

extern "C" void kernel_launch(void* const* d_in, const int* in_sizes, int n_in,
                              void* d_out, int out_size, void* d_ws, size_t ws_size,
                              hipStream_t stream) {
    const float* x0  = (const float*)d_in[0];  // [B,S,D]
    const float* adj = (const float*)d_in[1];  // [B,S,S]
    const float* W1  = (const float*)d_in[2];  // [L,D,D]
    const float* b1  = (const float*)d_in[3];  // [L,D]
    const float* W2  = (const float*)d_in[4];
    const float* b2  = (const float*)d_in[5];
    const float* U   = (const float*)d_in[6];  // [1,513,513]
    float* out = (float*)d_out;

    char* ws = (char*)d_ws;
    const size_t MB = 1u << 20;
    const long bAdj = (long)SS * SS, bAct = (long)SS * DD;
    const long DD2 = (long)DD * DD;
    _Float16* adjcat = (_Float16*)(ws);            // 32 MB: 16 mats (8 natural, 8 transposed)
    _Float16* x0t  = (_Float16*)(ws + 32 * MB);    // 8 MB x0^T fp16
    _Float16* x0h  = (_Float16*)(ws + 40 * MB);    // 8 MB x0 fp16 natural
    _Float16* u1   = (_Float16*)(ws + 48 * MB);    // 16 MB Y (both streams)
    _Float16* u2   = (_Float16*)(ws + 64 * MB);    // 16 MB X' natural (both streams)
    _Float16* u3   = (_Float16*)(ws + 80 * MB);    // 16 MB X'^T (both streams)
    _Float16* h12  = (_Float16*)(ws + 96 * MB);    // 16 MB h1 (z 0-7) + h2 (z 8-15)
    _Float16* t1h  = (_Float16*)(ws + 112 * MB);   // [8192][576] 9.44 MB
    _Float16* Wcat = (_Float16*)(ws + 122 * MB);   // [2 layer][2 stream][512][512] = 2 MB (122-124)
    _Float16* UT   = (_Float16*)(ws + 124 * MB);   // [640][512] zero-padded, 0.64 MB
    float* Ubias   = (float*)(ws + 125 * MB);          // [576]
    float* bcat    = (float*)(ws + 125 * MB + 4096);   // [2][2][512]
    float* rden12  = (float*)(ws + 125 * MB + 16384);  // [16384]

    dim3 tb(64, 4);
    // fused small preps: Wcat (z 0-3), UT + Ubias + bcat (z 4)
    wprep_k<<<dim3(10, 8, 5), tb, 0, stream>>>(W1, W2, U, b1, b2, Wcat, UT, Ubias, bcat);
    prep_k<float, false, true, true><<<dim3(8, 16, BATCH), tb, 0, stream>>>(
        x0, DD, bAct, x0h, DD, bAct, x0t, SS, bAct, SS, DD, DD, SS);
    // pruned adjacency: natural (z 0-7) + transposed (z 8-15) in ONE fp32 pass
    prep_k<float, true, true, true><<<dim3(16, 16, BATCH), tb, 0, stream>>>(
        adj, SS, bAdj, adjcat, SS, bAdj, adjcat + 8 * bAdj, SS, bAdj, SS, SS, SS, SS);
    // merged denominators: rows 0-8191 -> rden1, rows 8192-16383 -> rden2
    rsum_k<<<16384 / 4, 256, 0, stream>>>(adjcat, rden12, 16384);

    dim3 gAgg(SS / GBM, DD / GBN, 16);           // 512 blocks, 2/CU
    dim3 gWmm(BATCH * SS / GBM, DD / GBN, 2);    // 512 blocks (both streams)
    dim3 gT1(BATCH * SS / GBM, 5, 1);            // 320 blocks, N padded to 640
    dim3 gSc(SS / GBM, SS / GBN, BATCH);         // 512 blocks

    // layer 0 aggregation, both streams (z = stream*8 + batch)
    gemm_k<1><<<gAgg, 512, 0, stream>>>(adjcat, x0t, u1, nullptr, SS, DD, SS, SS, SS, DD,
                                        bAdj, bAct, bAct, 7, x0h, DD, bAct, 7, nullptr);
    // layer 0 transform, both streams in one z=2 dispatch; epilogue also writes X'^T -> u3
    gemm_k<5><<<gWmm, 512, 0, stream>>>(u1, Wcat, u2, u3, BATCH * SS, DD, DD, DD, DD, DD,
                                        8 * bAct, DD2, 8 * bAct, 1,
                                        bcat, 8192, 512, 1, rden12);
    // layer 1 aggregation (B = X'^T, self-loop add = X' natural)
    gemm_k<1><<<gAgg, 512, 0, stream>>>(adjcat, u3, u1, nullptr, SS, DD, SS, SS, SS, DD,
                                        bAdj, bAct, bAct, 15, u2, DD, bAct, 15, nullptr);
    // layer 1 transform -> h1 (z=0) / h2 (z=1)
    gemm_k<2><<<gWmm, 512, 0, stream>>>(u1, Wcat + 2 * DD2, h12, nullptr,
                                        BATCH * SS, DD, DD, DD, DD, DD,
                                        8 * bAct, DD2, 8 * bAct, 1,
                                        bcat + 1024, 8192, 512, 1, rden12);

    // t1 = [h1|1]*U
    gemm_k<3><<<gT1, 512, 0, stream>>>(h12, UT, t1h, nullptr, BATCH * SS, 576, DD, DD, DD, 576,
                                       0, 0, 0, 0, Ubias, 0, 0, 0, nullptr);
    // score[b,x,y] = t1[b,x,:512].h2[b,y,:512] + t1[b,x,512]
    gemm_k<4><<<gSc, 512, 0, stream>>>(t1h, h12 + 8 * bAct, out, nullptr, SS, SS, DD, 576, DD, SS,
                                       (long)SS * 576, bAct, (long)SS * SS, 15,
                                       t1h + 512, 576, (long)SS * 576, 15, nullptr);
}

// Round 9
// 157.246 us; speedup vs baseline: 1.4694x; 1.0708x over previous
//
#include <hip/hip_runtime.h>

#define SS 1024
#define DD 512
#define BATCH 8
#define MIN_T 0.1f
#define MAX_T 0.9f

using half8  = __attribute__((ext_vector_type(8))) _Float16;
using floatx4 = __attribute__((ext_vector_type(4))) float;

typedef const __attribute__((address_space(1))) void gvoid;
typedef __attribute__((address_space(3))) void lvoid;

// ---------------- mega prep: one dispatch, three task classes ----------------
// blocks [0,2048): adj prune+cast natural & transposed + fp32 row/col partial sums
// blocks [2048,3072): x0 cast natural + transposed
// blocks [3072,3472): Wcat transposes (z 0-3), UT transpose + Ubias/bcat pack (z 4)
// part layout: [16384][16] fp32; row = strm*8192 + z*1024 + r (strm 0 = nat rows, 1 = cols)
__global__ void mega_k(const float* __restrict__ x0, const float* __restrict__ adj,
                       const float* __restrict__ W1, const float* __restrict__ W2,
                       const float* __restrict__ U, const float* __restrict__ b1,
                       const float* __restrict__ b2,
                       _Float16* __restrict__ adjcat, _Float16* __restrict__ x0h,
                       _Float16* __restrict__ x0t, _Float16* __restrict__ Wcat,
                       _Float16* __restrict__ UT, float* __restrict__ Ubias,
                       float* __restrict__ bcat, float* __restrict__ part) {
    __shared__ float lt[64][65];
    __shared__ float csum[4][64];
    const int id = blockIdx.x;
    const int tx = threadIdx.x, ty = threadIdx.y;  // 64 x 4

    if (id < 2048) {
        // ---- adjacency task: z = batch, (x,y) = 64x64 tile (16x16 tiles) ----
        int z = id >> 8, y = (id >> 4) & 15, x = id & 15;
        int r0 = y * 64, c0 = x * 64;
        const float* src = adj + (size_t)z * SS * SS;
        _Float16* dN = adjcat + (size_t)z * SS * SS;
        _Float16* dT = adjcat + (size_t)(8 + z) * SS * SS;
        float colacc = 0.f;
#pragma unroll
        for (int it = 0; it < 16; ++it) {
            int r = r0 + ty + it * 4, c = c0 + tx;
            float v = src[(size_t)r * SS + c];
            v = (v >= MIN_T && v <= MAX_T) ? v : 0.f;
            dN[(size_t)r * SS + c] = (_Float16)v;
            lt[tx][ty + it * 4] = v;
            colacc += v;
            float rs = v;  // row partial: this wave (fixed ty) holds row r across lanes
#pragma unroll
            for (int m = 32; m > 0; m >>= 1) rs += __shfl_xor(rs, m, 64);
            if (tx == 0) part[((size_t)z * SS + r) * 16 + x] = rs;
        }
        csum[ty][tx] = colacc;
        __syncthreads();
#pragma unroll
        for (int it = 0; it < 16; ++it) {
            int tr = c0 + ty + it * 4, tc = r0 + tx;
            dT[(size_t)tr * SS + tc] = (_Float16)lt[ty + it * 4][tx];
        }
        if (ty == 0) {
            float cs = csum[0][tx] + csum[1][tx] + csum[2][tx] + csum[3][tx];
            part[(size_t)131072 + ((size_t)z * SS + (c0 + tx)) * 16 + y] = cs;
        }
    } else if (id < 3072) {
        // ---- x0 task: [1024][512] -> x0h natural + x0t transposed ----
        int rel = id - 2048;
        int z = rel >> 7, y = (rel >> 3) & 15, x = rel & 7;
        int r0 = y * 64, c0 = x * 64;
        const float* src = x0 + (size_t)z * SS * DD;
        _Float16* dN = x0h + (size_t)z * SS * DD;
        _Float16* dT = x0t + (size_t)z * SS * DD;
#pragma unroll
        for (int it = 0; it < 16; ++it) {
            int r = r0 + ty + it * 4, c = c0 + tx;
            float v = src[(size_t)r * DD + c];
            dN[(size_t)r * DD + c] = (_Float16)v;
            lt[tx][ty + it * 4] = v;
        }
        __syncthreads();
#pragma unroll
        for (int it = 0; it < 16; ++it) {
            int tr = c0 + ty + it * 4, tc = r0 + tx;
            dT[(size_t)tr * SS + tc] = (_Float16)lt[ty + it * 4][tx];
        }
    } else {
        // ---- weight/U task: (10 x, 8 y, 5 z) flattened ----
        int rel = id - 3072;
        int z = rel / 80, rem = rel % 80;
        int y = rem / 10, x = rem % 10;
        const float* src;
        _Float16* dT;
        int sld, srcR, srcC, dTR, dTC, ldT;
        if (z < 4) {
            int l = z >> 1, st = z & 1;
            src = (st ? W2 : W1) + (size_t)l * DD * DD;
            sld = DD; srcR = DD; srcC = DD;
            dT = Wcat + (size_t)z * DD * DD; ldT = DD; dTR = DD; dTC = DD;
        } else {
            src = U; sld = 513; srcR = 512; srcC = 513;
            dT = UT; ldT = DD; dTR = 640; dTC = DD;
        }
        int c0 = x * 64, r0 = y * 64;
#pragma unroll
        for (int it = 0; it < 16; ++it) {
            int r = r0 + ty + it * 4, c = c0 + tx;
            float v = 0.f;
            if (r < srcR && c < srcC) v = src[(size_t)r * sld + c];
            lt[tx][ty + it * 4] = v;
        }
        __syncthreads();
#pragma unroll
        for (int it = 0; it < 16; ++it) {
            int tr = c0 + ty + it * 4, tc = r0 + tx;
            if (tr < dTR && tc < dTC)
                dT[(size_t)tr * ldT + tc] = (_Float16)lt[ty + it * 4][tx];
        }
        if (z == 4 && x == 0 && y == 0) {
            int tid = ty * 64 + tx;
            for (int i = tid; i < 2048; i += 256) {
                int l = i >> 10, st = (i >> 9) & 1, n = i & 511;
                bcat[i] = (st == 0) ? b1[l * 512 + n] : b2[l * 512 + n];
            }
            for (int i = tid; i < 576; i += 256) Ubias[i] = (i < 513) ? U[512 * 513 + i] : 0.f;
        }
    }
}

// ---------------- reduce 16 partials per row -> rden = 1/(sum+1) ----------------
__global__ void rsum2_k(const float* __restrict__ part, float* __restrict__ rden) {
    int row = blockIdx.x * 256 + threadIdx.x;  // 0..16383
    const float* p = part + (size_t)row * 16;
    float s = 0.f;
#pragma unroll
    for (int i = 0; i < 16; ++i) s += p[i];
    rden[row] = 1.0f / (s + 1.0f);
}

// ---------------- MFMA GEMM: C = A[M][K] * B[N][K]^T, fp16 in / fp32 acc ----------------
// 128x128 tile, 512 threads = 8 waves (2x4), 64x32 per wave.
// XCD-chunked block swizzle (grid %8==0). z-batch: A += z*bA, B += (z&zmB)*bB, C += z*bC.
// EPI: 1 = agg + fp16X add; 2 = wmm relu((acc+bias[n])*rden[m]);
//      5 = EPI2 + transposed store to Cv2; 3 = t1 acc+e0f[n], guard n<N;
//      4 = score acc+(float)e0h[m*e0ld] (C fp32)
constexpr int GBM = 128, GBN = 128, GBK = 64;

template <int EPI>
__global__ __launch_bounds__(512, 4) void gemm_k(
    const _Float16* __restrict__ A, const _Float16* __restrict__ B, void* __restrict__ Cv,
    void* __restrict__ Cv2,
    int M, int N, int K, int lda, int ldb, int ldc,
    long bA, long bB, long bC, int zmB,
    const void* __restrict__ e0, int e0ld, long bE0, int zmE,
    const float* __restrict__ e1) {
    __shared__ _Float16 lA[2][GBM * GBK];  // [128][64], 8x16B chunks/row, source-swizzled
    __shared__ _Float16 lB[2][GBN * GBK];  // [128][64]

    const int gx = gridDim.x, gy = gridDim.y;
    const int nwg = gx * gy * gridDim.z;
    const int orig = (blockIdx.z * gy + blockIdx.y) * gx + blockIdx.x;
    const int w = (orig & 7) * (nwg >> 3) + (orig >> 3);
    const int bx = w % gx;
    const int wt = w / gx;
    const int by = wt % gy;
    const int z = wt / gy;

    A += (size_t)z * bA;
    B += (size_t)(z & zmB) * bB;
    const int m0 = bx * GBM, n0 = by * GBN;
    const int tid = threadIdx.x;
    const int lane = tid & 63, wv = tid >> 6;
    const int wr = wv >> 2, wc = wv & 3;  // 2x4 waves, 64x32 per wave

    auto stage = [&](int buf, int kt) {
#pragma unroll
        for (int it = 0; it < 2; ++it) {  // A: 1024 chunks
            int q = it * 512 + tid;
            int r = q >> 3, cp = q & 7, cl = cp ^ (r & 7);
            const _Float16* g = A + (size_t)(m0 + r) * lda + kt + cl * 8;
            __builtin_amdgcn_global_load_lds((gvoid*)g,
                (lvoid*)(&lA[buf][(it * 512 + wv * 64) * 8]), 16, 0, 0);
        }
#pragma unroll
        for (int it = 0; it < 2; ++it) {  // B: 1024 chunks
            int q = it * 512 + tid;
            int r = q >> 3, cp = q & 7, cl = cp ^ (r & 7);
            const _Float16* g = B + (size_t)(n0 + r) * ldb + kt + cl * 8;
            __builtin_amdgcn_global_load_lds((gvoid*)g,
                (lvoid*)(&lB[buf][(it * 512 + wv * 64) * 8]), 16, 0, 0);
        }
    };

    floatx4 acc[4][2] = {};

    stage(0, 0);
    asm volatile("s_waitcnt vmcnt(0)");
    __syncthreads();
    int cur = 0;
    for (int kt = 0; kt < K; kt += GBK) {
        int nxt = kt + GBK;
        if (nxt < K) stage(cur ^ 1, nxt);
#pragma unroll
        for (int kk = 0; kk < 2; ++kk) {
            half8 af[4], bf[2];
#pragma unroll
            for (int i = 0; i < 4; ++i) {
                int row = wr * 64 + i * 16 + (lane & 15);
                int cl = kk * 4 + (lane >> 4);
                int cp = cl ^ (row & 7);
                af[i] = *(const half8*)&lA[cur][row * 64 + cp * 8];
            }
#pragma unroll
            for (int j = 0; j < 2; ++j) {
                int row = wc * 32 + j * 16 + (lane & 15);
                int cl = kk * 4 + (lane >> 4);
                int cp = cl ^ (row & 7);
                bf[j] = *(const half8*)&lB[cur][row * 64 + cp * 8];
            }
#pragma unroll
            for (int i = 0; i < 4; ++i)
#pragma unroll
                for (int j = 0; j < 2; ++j)
                    acc[i][j] = __builtin_amdgcn_mfma_f32_16x16x32_f16(af[i], bf[j], acc[i][j], 0, 0, 0);
        }
        if (nxt < K) {
            asm volatile("s_waitcnt vmcnt(0)");
            __syncthreads();
        }
        cur ^= 1;
    }

    // epilogue: C map col=lane&15, row=(lane>>4)*4+r
    const int cm = (lane >> 4) * 4;
    const int cn = lane & 15;
    const long bAct = (long)SS * DD;
#pragma unroll
    for (int i = 0; i < 4; ++i) {
#pragma unroll
        for (int j = 0; j < 2; ++j) {
#pragma unroll
            for (int r = 0; r < 4; ++r) {
                int m = m0 + wr * 64 + i * 16 + cm + r;
                int n = n0 + wc * 32 + j * 16 + cn;
                float v = acc[i][j][r];
                if constexpr (EPI == 1) {
                    const _Float16* X = (const _Float16*)e0 + (size_t)(z & zmE) * bE0;
                    v += (float)X[(size_t)m * e0ld + n];
                    ((_Float16*)Cv)[(size_t)z * bC + (size_t)m * ldc + n] = (_Float16)v;
                } else if constexpr (EPI == 2 || EPI == 5) {
                    const float* bb = (const float*)e0 + (size_t)(z & zmE) * bE0;
                    v = (v + bb[n]) * e1[(size_t)z * e0ld + m];
                    v = v > 0.f ? v : 0.f;
                    ((_Float16*)Cv)[(size_t)z * bC + (size_t)m * ldc + n] = (_Float16)v;
                    if constexpr (EPI == 5) {
                        int bt = m >> 10, s = m & 1023;
                        ((_Float16*)Cv2)[(size_t)(z * 8 + bt) * bAct + (size_t)n * SS + s] =
                            (_Float16)v;
                    }
                } else if constexpr (EPI == 3) {
                    if (n < N) {
                        v += ((const float*)e0)[n];
                        ((_Float16*)Cv)[(size_t)z * bC + (size_t)m * ldc + n] = (_Float16)v;
                    }
                } else {
                    const _Float16* tb = (const _Float16*)e0 + (size_t)(z & zmE) * bE0;
                    v += (float)tb[(size_t)m * e0ld];
                    ((float*)Cv)[(size_t)z * bC + (size_t)m * ldc + n] = v;
                }
            }
        }
    }
}

extern "C" void kernel_launch(void* const* d_in, const int* in_sizes, int n_in,
                              void* d_out, int out_size, void* d_ws, size_t ws_size,
                              hipStream_t stream) {
    const float* x0  = (const float*)d_in[0];  // [B,S,D]
    const float* adj = (const float*)d_in[1];  // [B,S,S]
    const float* W1  = (const float*)d_in[2];  // [L,D,D]
    const float* b1  = (const float*)d_in[3];  // [L,D]
    const float* W2  = (const float*)d_in[4];
    const float* b2  = (const float*)d_in[5];
    const float* U   = (const float*)d_in[6];  // [1,513,513]
    float* out = (float*)d_out;

    char* ws = (char*)d_ws;
    const size_t MB = 1u << 20;
    const long bAdj = (long)SS * SS, bAct = (long)SS * DD;
    const long DD2 = (long)DD * DD;
    _Float16* adjcat = (_Float16*)(ws);            // 32 MB: 16 mats (8 natural, 8 transposed)
    _Float16* x0t  = (_Float16*)(ws + 32 * MB);    // 8 MB x0^T fp16
    _Float16* x0h  = (_Float16*)(ws + 40 * MB);    // 8 MB x0 fp16 natural
    _Float16* u1   = (_Float16*)(ws + 48 * MB);    // 16 MB Y (both streams)
    _Float16* u2   = (_Float16*)(ws + 64 * MB);    // 16 MB X' natural (both streams)
    _Float16* u3   = (_Float16*)(ws + 80 * MB);    // 16 MB X'^T (both streams)
    _Float16* h12  = (_Float16*)(ws + 96 * MB);    // 16 MB h1 (z 0-7) + h2 (z 8-15)
    _Float16* t1h  = (_Float16*)(ws + 112 * MB);   // [8192][576] 9.44 MB
    _Float16* Wcat = (_Float16*)(ws + 122 * MB);   // [2 layer][2 stream][512][512] = 2 MB (122-124)
    _Float16* UT   = (_Float16*)(ws + 124 * MB);   // [640][512] zero-padded, 0.64 MB
    float* Ubias   = (float*)(ws + 125 * MB);          // [576]
    float* bcat    = (float*)(ws + 125 * MB + 4096);   // [2][2][512]
    float* rden12  = (float*)(ws + 125 * MB + 16384);  // [16384] (64 KB)
    float* part    = (float*)(ws + 126 * MB);          // [16384][16] = 1 MB

    // one mega prep dispatch: adj (2048 blocks) + x0 (1024) + weights/U/bias (400)
    mega_k<<<3472, dim3(64, 4), 0, stream>>>(x0, adj, W1, W2, U, b1, b2,
                                             adjcat, x0h, x0t, Wcat, UT, Ubias, bcat, part);
    // reduce partials -> rden12 (rows 0-8191 nat, 8192-16383 transposed)
    rsum2_k<<<64, 256, 0, stream>>>(part, rden12);

    dim3 gAgg(SS / GBM, DD / GBN, 16);           // 512 blocks, 2/CU
    dim3 gWmm(BATCH * SS / GBM, DD / GBN, 2);    // 512 blocks (both streams)
    dim3 gT1(BATCH * SS / GBM, 5, 1);            // 320 blocks, N padded to 640
    dim3 gSc(SS / GBM, SS / GBN, BATCH);         // 512 blocks

    // layer 0 aggregation, both streams (z = stream*8 + batch)
    gemm_k<1><<<gAgg, 512, 0, stream>>>(adjcat, x0t, u1, nullptr, SS, DD, SS, SS, SS, DD,
                                        bAdj, bAct, bAct, 7, x0h, DD, bAct, 7, nullptr);
    // layer 0 transform, both streams in one z=2 dispatch; epilogue also writes X'^T -> u3
    gemm_k<5><<<gWmm, 512, 0, stream>>>(u1, Wcat, u2, u3, BATCH * SS, DD, DD, DD, DD, DD,
                                        8 * bAct, DD2, 8 * bAct, 1,
                                        bcat, 8192, 512, 1, rden12);
    // layer 1 aggregation (B = X'^T, self-loop add = X' natural)
    gemm_k<1><<<gAgg, 512, 0, stream>>>(adjcat, u3, u1, nullptr, SS, DD, SS, SS, SS, DD,
                                        bAdj, bAct, bAct, 15, u2, DD, bAct, 15, nullptr);
    // layer 1 transform -> h1 (z=0) / h2 (z=1)
    gemm_k<2><<<gWmm, 512, 0, stream>>>(u1, Wcat + 2 * DD2, h12, nullptr,
                                        BATCH * SS, DD, DD, DD, DD, DD,
                                        8 * bAct, DD2, 8 * bAct, 1,
                                        bcat + 1024, 8192, 512, 1, rden12);

    // t1 = [h1|1]*U
    gemm_k<3><<<gT1, 512, 0, stream>>>(h12, UT, t1h, nullptr, BATCH * SS, 576, DD, DD, DD, 576,
                                       0, 0, 0, 0, Ubias, 0, 0, 0, nullptr);
    // score[b,x,y] = t1[b,x,:512].h2[b,y,:512] + t1[b,x,512]
    gemm_k<4><<<gSc, 512, 0, stream>>>(t1h, h12 + 8 * bAct, out, nullptr, SS, SS, DD, 576, DD, SS,
                                       (long)SS * 576, bAct, (long)SS * SS, 15,
                                       t1h + 512, 576, (long)SS * 576, 15, nullptr);
}

// Round 10
// 151.287 us; speedup vs baseline: 1.5273x; 1.0394x over previous
//
#include <hip/hip_runtime.h>

#define SS 1024
#define DD 512
#define BATCH 8
#define MIN_T 0.1f
#define MAX_T 0.9f

using half4  = __attribute__((ext_vector_type(4))) _Float16;
using half8  = __attribute__((ext_vector_type(8))) _Float16;
using floatx4 = __attribute__((ext_vector_type(4))) float;

typedef const __attribute__((address_space(1))) void gvoid;
typedef __attribute__((address_space(3))) void lvoid;

// ---------------- mega prep: one dispatch, three task classes ----------------
// blocks [0,2048): adj prune+cast natural & transposed + fp32 row/col partial sums
// blocks [2048,3072): x0 cast natural + transposed
// blocks [3072,3472): Wcat transposes (z 0-3), UT transpose + Ubias/bcat pack (z 4)
// part layout: [16384][16] fp32; rows 0-8191 = natural row sums, 8192-16383 = col sums
__global__ void mega_k(const float* __restrict__ x0, const float* __restrict__ adj,
                       const float* __restrict__ W1, const float* __restrict__ W2,
                       const float* __restrict__ U, const float* __restrict__ b1,
                       const float* __restrict__ b2,
                       _Float16* __restrict__ adjcat, _Float16* __restrict__ x0h,
                       _Float16* __restrict__ x0t, _Float16* __restrict__ Wcat,
                       _Float16* __restrict__ UT, float* __restrict__ Ubias,
                       float* __restrict__ bcat, float* __restrict__ part) {
    __shared__ float lt[64][68];    // fp32 tile, transposed layout lt[col][row]
    __shared__ float csum[16][68];  // per-row-group column partials
    const int id = blockIdx.x;
    const int tx = threadIdx.x, ty = threadIdx.y;  // 64 x 4
    const int tid = ty * 64 + tx;
    const int i16 = tid & 15;        // 16 threads per row, 4 cols each
    const int g = tid >> 4;          // row-group 0..15

    if (id < 2048) {
        // ---- adjacency task: z = batch, (x,y) = 64x64 tile of 16x16 grid ----
        int z = id >> 8, y = (id >> 4) & 15, x = id & 15;
        int r0 = y * 64, c0 = x * 64;
        const float* src = adj + (size_t)z * SS * SS;
        _Float16* dN = adjcat + (size_t)z * SS * SS;
        _Float16* dT = adjcat + (size_t)(8 + z) * SS * SS;
        const int c4 = i16 * 4;
        float colacc[4] = {};
#pragma unroll
        for (int p = 0; p < 4; ++p) {
            int r = p * 16 + g;
            floatx4 v = *(const floatx4*)&src[(size_t)(r0 + r) * SS + c0 + c4];
#pragma unroll
            for (int j = 0; j < 4; ++j) {
                float f = v[j];
                v[j] = (f >= MIN_T && f <= MAX_T) ? f : 0.f;
                colacc[j] += v[j];
            }
            half4 h = {(_Float16)v[0], (_Float16)v[1], (_Float16)v[2], (_Float16)v[3]};
            *(half4*)&dN[(size_t)(r0 + r) * SS + c0 + c4] = h;
            lt[c4][r] = v[0]; lt[c4 + 1][r] = v[1]; lt[c4 + 2][r] = v[2]; lt[c4 + 3][r] = v[3];
            float rs = v[0] + v[1] + v[2] + v[3];
#pragma unroll
            for (int m = 8; m > 0; m >>= 1) rs += __shfl_xor(rs, m, 16);
            if (i16 == 0) part[((size_t)z * SS + r0 + r) * 16 + x] = rs;
        }
        *(floatx4*)&csum[g][c4] = *(floatx4*)colacc;
        __syncthreads();
#pragma unroll
        for (int p = 0; p < 4; ++p) {
            int cc = p * 16 + g;               // transposed-row = original col
            int rr = c4;                        // 4 consecutive original rows
            floatx4 v = *(const floatx4*)&lt[cc][rr];
            half4 h = {(_Float16)v[0], (_Float16)v[1], (_Float16)v[2], (_Float16)v[3]};
            *(half4*)&dT[(size_t)(c0 + cc) * SS + r0 + rr] = h;
        }
        if (ty == 0) {  // column sums: c = tx
            float cs = 0.f;
#pragma unroll
            for (int q = 0; q < 16; ++q) cs += csum[q][tx];
            part[(size_t)131072 + ((size_t)z * SS + c0 + tx) * 16 + y] = cs;
        }
    } else if (id < 3072) {
        // ---- x0 task: [1024][512] per batch -> x0h natural + x0t transposed ----
        int rel = id - 2048;
        int z = rel >> 7, y = (rel >> 3) & 15, x = rel & 7;
        int r0 = y * 64, c0 = x * 64;
        const float* src = x0 + (size_t)z * SS * DD;
        _Float16* dN = x0h + (size_t)z * SS * DD;
        _Float16* dT = x0t + (size_t)z * SS * DD;
        const int c4 = i16 * 4;
#pragma unroll
        for (int p = 0; p < 4; ++p) {
            int r = p * 16 + g;
            floatx4 v = *(const floatx4*)&src[(size_t)(r0 + r) * DD + c0 + c4];
            half4 h = {(_Float16)v[0], (_Float16)v[1], (_Float16)v[2], (_Float16)v[3]};
            *(half4*)&dN[(size_t)(r0 + r) * DD + c0 + c4] = h;
            lt[c4][r] = v[0]; lt[c4 + 1][r] = v[1]; lt[c4 + 2][r] = v[2]; lt[c4 + 3][r] = v[3];
        }
        __syncthreads();
#pragma unroll
        for (int p = 0; p < 4; ++p) {
            int cc = p * 16 + g;
            int rr = c4;
            floatx4 v = *(const floatx4*)&lt[cc][rr];
            half4 h = {(_Float16)v[0], (_Float16)v[1], (_Float16)v[2], (_Float16)v[3]};
            *(half4*)&dT[(size_t)(c0 + cc) * SS + r0 + rr] = h;
        }
    } else {
        // ---- weight/U task: (10 x, 8 y, 5 z) flattened, scalar (small) ----
        int rel = id - 3072;
        int z = rel / 80, rem = rel % 80;
        int y = rem / 10, x = rem % 10;
        const float* src;
        _Float16* dT;
        int sld, srcR, srcC, dTR, dTC, ldT;
        if (z < 4) {
            int l = z >> 1, st = z & 1;
            src = (st ? W2 : W1) + (size_t)l * DD * DD;
            sld = DD; srcR = DD; srcC = DD;
            dT = Wcat + (size_t)z * DD * DD; ldT = DD; dTR = DD; dTC = DD;
        } else {
            src = U; sld = 513; srcR = 512; srcC = 513;
            dT = UT; ldT = DD; dTR = 640; dTC = DD;
        }
        int c0 = x * 64, r0 = y * 64;
#pragma unroll
        for (int it = 0; it < 16; ++it) {
            int r = r0 + ty + it * 4, c = c0 + tx;
            float v = 0.f;
            if (r < srcR && c < srcC) v = src[(size_t)r * sld + c];
            lt[tx][ty + it * 4] = v;
        }
        __syncthreads();
#pragma unroll
        for (int it = 0; it < 16; ++it) {
            int tr = c0 + ty + it * 4, tc = r0 + tx;
            if (tr < dTR && tc < dTC)
                dT[(size_t)tr * ldT + tc] = (_Float16)lt[ty + it * 4][tx];
        }
        if (z == 4 && x == 0 && y == 0) {
            for (int i = tid; i < 2048; i += 256) {
                int l = i >> 10, st = (i >> 9) & 1, n = i & 511;
                bcat[i] = (st == 0) ? b1[l * 512 + n] : b2[l * 512 + n];
            }
            for (int i = tid; i < 576; i += 256) Ubias[i] = (i < 513) ? U[512 * 513 + i] : 0.f;
        }
    }
}

// ---------------- reduce 16 partials per row -> rden = 1/(sum+1) ----------------
__global__ void rsum2_k(const float* __restrict__ part, float* __restrict__ rden) {
    int row = blockIdx.x * 256 + threadIdx.x;  // 0..16383
    const float* p = part + (size_t)row * 16;
    float s = 0.f;
#pragma unroll
    for (int i = 0; i < 16; ++i) s += p[i];
    rden[row] = 1.0f / (s + 1.0f);
}

// ---------------- MFMA GEMM: C = A[M][K] * B[N][K]^T, fp16 in / fp32 acc ----------------
// 128x128 tile, 512 threads = 8 waves (2x4), 64x32 per wave.
// XCD-chunked block swizzle (grid %8==0). z-batch: A += z*bA, B += (z&zmB)*bB, C += z*bC.
// EPI: 1 = agg + fp16X add; 2 = wmm relu((acc+bias[n])*rden[m]);
//      5 = EPI2 + transposed store to Cv2; 3 = t1 acc+e0f[n], guard n<N;
//      4 = score acc+(float)e0h[m*e0ld] (C fp32)
constexpr int GBM = 128, GBN = 128, GBK = 64;

template <int EPI>
__global__ __launch_bounds__(512, 4) void gemm_k(
    const _Float16* __restrict__ A, const _Float16* __restrict__ B, void* __restrict__ Cv,
    void* __restrict__ Cv2,
    int M, int N, int K, int lda, int ldb, int ldc,
    long bA, long bB, long bC, int zmB,
    const void* __restrict__ e0, int e0ld, long bE0, int zmE,
    const float* __restrict__ e1) {
    __shared__ _Float16 lA[2][GBM * GBK];  // [128][64], 8x16B chunks/row, source-swizzled
    __shared__ _Float16 lB[2][GBN * GBK];  // [128][64]

    const int gx = gridDim.x, gy = gridDim.y;
    const int nwg = gx * gy * gridDim.z;
    const int orig = (blockIdx.z * gy + blockIdx.y) * gx + blockIdx.x;
    const int w = (orig & 7) * (nwg >> 3) + (orig >> 3);
    const int bx = w % gx;
    const int wt = w / gx;
    const int by = wt % gy;
    const int z = wt / gy;

    A += (size_t)z * bA;
    B += (size_t)(z & zmB) * bB;
    const int m0 = bx * GBM, n0 = by * GBN;
    const int tid = threadIdx.x;
    const int lane = tid & 63, wv = tid >> 6;
    const int wr = wv >> 2, wc = wv & 3;  // 2x4 waves, 64x32 per wave

    auto stage = [&](int buf, int kt) {
#pragma unroll
        for (int it = 0; it < 2; ++it) {  // A: 1024 chunks
            int q = it * 512 + tid;
            int r = q >> 3, cp = q & 7, cl = cp ^ (r & 7);
            const _Float16* g = A + (size_t)(m0 + r) * lda + kt + cl * 8;
            __builtin_amdgcn_global_load_lds((gvoid*)g,
                (lvoid*)(&lA[buf][(it * 512 + wv * 64) * 8]), 16, 0, 0);
        }
#pragma unroll
        for (int it = 0; it < 2; ++it) {  // B: 1024 chunks
            int q = it * 512 + tid;
            int r = q >> 3, cp = q & 7, cl = cp ^ (r & 7);
            const _Float16* g = B + (size_t)(n0 + r) * ldb + kt + cl * 8;
            __builtin_amdgcn_global_load_lds((gvoid*)g,
                (lvoid*)(&lB[buf][(it * 512 + wv * 64) * 8]), 16, 0, 0);
        }
    };

    floatx4 acc[4][2] = {};

    stage(0, 0);
    asm volatile("s_waitcnt vmcnt(0)");
    __syncthreads();
    int cur = 0;
    for (int kt = 0; kt < K; kt += GBK) {
        int nxt = kt + GBK;
        if (nxt < K) stage(cur ^ 1, nxt);
#pragma unroll
        for (int kk = 0; kk < 2; ++kk) {
            half8 af[4], bf[2];
#pragma unroll
            for (int i = 0; i < 4; ++i) {
                int row = wr * 64 + i * 16 + (lane & 15);
                int cl = kk * 4 + (lane >> 4);
                int cp = cl ^ (row & 7);
                af[i] = *(const half8*)&lA[cur][row * 64 + cp * 8];
            }
#pragma unroll
            for (int j = 0; j < 2; ++j) {
                int row = wc * 32 + j * 16 + (lane & 15);
                int cl = kk * 4 + (lane >> 4);
                int cp = cl ^ (row & 7);
                bf[j] = *(const half8*)&lB[cur][row * 64 + cp * 8];
            }
#pragma unroll
            for (int i = 0; i < 4; ++i)
#pragma unroll
                for (int j = 0; j < 2; ++j)
                    acc[i][j] = __builtin_amdgcn_mfma_f32_16x16x32_f16(af[i], bf[j], acc[i][j], 0, 0, 0);
        }
        if (nxt < K) {
            asm volatile("s_waitcnt vmcnt(0)");
            __syncthreads();
        }
        cur ^= 1;
    }

    // epilogue: C map col=lane&15, row=(lane>>4)*4+r
    const int cm = (lane >> 4) * 4;
    const int cn = lane & 15;
    const long bAct = (long)SS * DD;
#pragma unroll
    for (int i = 0; i < 4; ++i) {
#pragma unroll
        for (int j = 0; j < 2; ++j) {
#pragma unroll
            for (int r = 0; r < 4; ++r) {
                int m = m0 + wr * 64 + i * 16 + cm + r;
                int n = n0 + wc * 32 + j * 16 + cn;
                float v = acc[i][j][r];
                if constexpr (EPI == 1) {
                    const _Float16* X = (const _Float16*)e0 + (size_t)(z & zmE) * bE0;
                    v += (float)X[(size_t)m * e0ld + n];
                    ((_Float16*)Cv)[(size_t)z * bC + (size_t)m * ldc + n] = (_Float16)v;
                } else if constexpr (EPI == 2 || EPI == 5) {
                    const float* bb = (const float*)e0 + (size_t)(z & zmE) * bE0;
                    v = (v + bb[n]) * e1[(size_t)z * e0ld + m];
                    v = v > 0.f ? v : 0.f;
                    ((_Float16*)Cv)[(size_t)z * bC + (size_t)m * ldc + n] = (_Float16)v;
                    if constexpr (EPI == 5) {
                        int bt = m >> 10, s = m & 1023;
                        ((_Float16*)Cv2)[(size_t)(z * 8 + bt) * bAct + (size_t)n * SS + s] =
                            (_Float16)v;
                    }
                } else if constexpr (EPI == 3) {
                    if (n < N) {
                        v += ((const float*)e0)[n];
                        ((_Float16*)Cv)[(size_t)z * bC + (size_t)m * ldc + n] = (_Float16)v;
                    }
                } else {
                    const _Float16* tb = (const _Float16*)e0 + (size_t)(z & zmE) * bE0;
                    v += (float)tb[(size_t)m * e0ld];
                    ((float*)Cv)[(size_t)z * bC + (size_t)m * ldc + n] = v;
                }
            }
        }
    }
}

extern "C" void kernel_launch(void* const* d_in, const int* in_sizes, int n_in,
                              void* d_out, int out_size, void* d_ws, size_t ws_size,
                              hipStream_t stream) {
    const float* x0  = (const float*)d_in[0];  // [B,S,D]
    const float* adj = (const float*)d_in[1];  // [B,S,S]
    const float* W1  = (const float*)d_in[2];  // [L,D,D]
    const float* b1  = (const float*)d_in[3];  // [L,D]
    const float* W2  = (const float*)d_in[4];
    const float* b2  = (const float*)d_in[5];
    const float* U   = (const float*)d_in[6];  // [1,513,513]
    float* out = (float*)d_out;

    char* ws = (char*)d_ws;
    const size_t MB = 1u << 20;
    const long bAdj = (long)SS * SS, bAct = (long)SS * DD;
    const long DD2 = (long)DD * DD;
    _Float16* adjcat = (_Float16*)(ws);            // 32 MB: 16 mats (8 natural, 8 transposed)
    _Float16* x0t  = (_Float16*)(ws + 32 * MB);    // 8 MB x0^T fp16
    _Float16* x0h  = (_Float16*)(ws + 40 * MB);    // 8 MB x0 fp16 natural
    _Float16* u1   = (_Float16*)(ws + 48 * MB);    // 16 MB Y (both streams)
    _Float16* u2   = (_Float16*)(ws + 64 * MB);    // 16 MB X' natural (both streams)
    _Float16* u3   = (_Float16*)(ws + 80 * MB);    // 16 MB X'^T (both streams)
    _Float16* h12  = (_Float16*)(ws + 96 * MB);    // 16 MB h1 (z 0-7) + h2 (z 8-15)
    _Float16* t1h  = (_Float16*)(ws + 112 * MB);   // [8192][576] 9.44 MB
    _Float16* Wcat = (_Float16*)(ws + 122 * MB);   // [2 layer][2 stream][512][512] = 2 MB (122-124)
    _Float16* UT   = (_Float16*)(ws + 124 * MB);   // [640][512] zero-padded, 0.64 MB
    float* Ubias   = (float*)(ws + 125 * MB);          // [576]
    float* bcat    = (float*)(ws + 125 * MB + 4096);   // [2][2][512]
    float* rden12  = (float*)(ws + 125 * MB + 16384);  // [16384] (64 KB)
    float* part    = (float*)(ws + 126 * MB);          // [16384][16] = 1 MB

    // one mega prep dispatch: adj (2048 blocks) + x0 (1024) + weights/U/bias (400)
    mega_k<<<3472, dim3(64, 4), 0, stream>>>(x0, adj, W1, W2, U, b1, b2,
                                             adjcat, x0h, x0t, Wcat, UT, Ubias, bcat, part);
    // reduce partials -> rden12 (rows 0-8191 nat, 8192-16383 transposed)
    rsum2_k<<<64, 256, 0, stream>>>(part, rden12);

    dim3 gAgg(SS / GBM, DD / GBN, 16);           // 512 blocks, 2/CU
    dim3 gWmm(BATCH * SS / GBM, DD / GBN, 2);    // 512 blocks (both streams)
    dim3 gT1(BATCH * SS / GBM, 5, 1);            // 320 blocks, N padded to 640
    dim3 gSc(SS / GBM, SS / GBN, BATCH);         // 512 blocks

    // layer 0 aggregation, both streams (z = stream*8 + batch)
    gemm_k<1><<<gAgg, 512, 0, stream>>>(adjcat, x0t, u1, nullptr, SS, DD, SS, SS, SS, DD,
                                        bAdj, bAct, bAct, 7, x0h, DD, bAct, 7, nullptr);
    // layer 0 transform, both streams in one z=2 dispatch; epilogue also writes X'^T -> u3
    gemm_k<5><<<gWmm, 512, 0, stream>>>(u1, Wcat, u2, u3, BATCH * SS, DD, DD, DD, DD, DD,
                                        8 * bAct, DD2, 8 * bAct, 1,
                                        bcat, 8192, 512, 1, rden12);
    // layer 1 aggregation (B = X'^T, self-loop add = X' natural)
    gemm_k<1><<<gAgg, 512, 0, stream>>>(adjcat, u3, u1, nullptr, SS, DD, SS, SS, SS, DD,
                                        bAdj, bAct, bAct, 15, u2, DD, bAct, 15, nullptr);
    // layer 1 transform -> h1 (z=0) / h2 (z=1)
    gemm_k<2><<<gWmm, 512, 0, stream>>>(u1, Wcat + 2 * DD2, h12, nullptr,
                                        BATCH * SS, DD, DD, DD, DD, DD,
                                        8 * bAct, DD2, 8 * bAct, 1,
                                        bcat + 1024, 8192, 512, 1, rden12);

    // t1 = [h1|1]*U
    gemm_k<3><<<gT1, 512, 0, stream>>>(h12, UT, t1h, nullptr, BATCH * SS, 576, DD, DD, DD, 576,
                                       0, 0, 0, 0, Ubias, 0, 0, 0, nullptr);
    // score[b,x,y] = t1[b,x,:512].h2[b,y,:512] + t1[b,x,512]
    gemm_k<4><<<gSc, 512, 0, stream>>>(t1h, h12 + 8 * bAct, out, nullptr, SS, SS, DD, 576, DD, SS,
                                       (long)SS * 576, bAct, (long)SS * SS, 15,
                                       t1h + 512, 576, (long)SS * 576, 15, nullptr);
}